// Round 5
// baseline (634.547 us; speedup 1.0000x reference)
//
#include <hip/hip_runtime.h>
#include <math.h>

#define NPAPER 100000
#define NAUTH  50000
#define DIM    128
#define NEDGE  500000
#define NCLS   16
#define NTOT   (2*NPAPER + NAUTH)   // concatenated CSR node count (C | W | R)

typedef unsigned int   uint;
typedef unsigned short ushort;
using short8 = __attribute__((ext_vector_type(8))) short;
using f32x4  = __attribute__((ext_vector_type(4))) float;

__device__ __forceinline__ float b2f(uint u) {
    return __uint_as_float(u << 16);
}
__device__ __forceinline__ ushort f2b(float f) {   // round-to-nearest-even
    uint x = __float_as_uint(f);
    return (ushort)((x + 0x7fffu + ((x >> 16) & 1u)) >> 16);
}

// global_load_lds: linear LDS dest (wave base + lane*16), per-lane global src.
#define GLD_LDS16(srcp, ldsp) \
    __builtin_amdgcn_global_load_lds( \
        (const __attribute__((address_space(1))) void*)(srcp), \
        (__attribute__((address_space(3))) void*)(ldsp), 16, 0, 0)

// ---------------------------------------------------------------------------
// prep 1: Bp[l]: [384][128] k-major f32 = [Wl0^T; Wl1^T; (Wr0+Wr1)^T]
//         Ba[l]: [256][128] = [Wl2^T; Wr2^T];  biasp/biasa
__global__ __launch_bounds__(256) void prep_weights(
    const float* __restrict__ Wl, const float* __restrict__ Wr,
    const float* __restrict__ bl,
    float* __restrict__ Bp, float* __restrict__ Ba,
    float* __restrict__ biasp, float* __restrict__ biasa)
{
    int t = blockIdx.x * 256 + threadIdx.x;
    if (t < 2*384*128) {
        int l = t / (384*128); int rem = t - l*(384*128);
        int k = rem >> 7, j = rem & 127;
        float v;
        if (k < 128)      v = Wl[((l*3+0)*128 + j)*128 + k];
        else if (k < 256) v = Wl[((l*3+1)*128 + j)*128 + (k-128)];
        else              v = Wr[((l*3+0)*128 + j)*128 + (k-256)]
                            + Wr[((l*3+1)*128 + j)*128 + (k-256)];
        Bp[t] = v;
        return;
    }
    t -= 2*384*128;
    if (t < 2*256*128) {
        int l = t / (256*128); int rem = t - l*(256*128);
        int k = rem >> 7, j = rem & 127;
        Ba[t] = (k < 128) ? Wl[((l*3+2)*128 + j)*128 + k]
                          : Wr[((l*3+2)*128 + j)*128 + (k-128)];
        return;
    }
    t -= 2*256*128;
    if (t < 256) { int l=t>>7, j=t&127; biasp[t] = bl[(l*3+0)*128+j] + bl[(l*3+1)*128+j]; return; }
    t -= 256;
    if (t < 256) { int l=t>>7, j=t&127; biasa[t] = bl[(l*3+2)*128+j]; return; }
}

// prep 2: residual fold + bf16 + PACK into MFMA-fragment order.
// Per 64-k step: [ks(2)][f(8)][lane(64)][8 elems]; staging = pure linear copy.
__device__ __forceinline__ size_t pack_off(int j, int k) {
    int kstep = k >> 6, ks = (k >> 5) & 1, g4 = (k >> 3) & 3, jj = k & 7;
    int f = j >> 4, l15 = j & 15;
    return (size_t)kstep*8192 + (size_t)(ks*512 + f*64 + g4*16 + l15)*8 + jj;
}

__global__ __launch_bounds__(256) void build_bt(
    const float* __restrict__ Bp, const float* __restrict__ Ba,
    const float* __restrict__ linp, const float* __restrict__ lina,
    ushort* __restrict__ Btp, ushort* __restrict__ Bta)
{
    int t = blockIdx.x * 256 + threadIdx.x;
    if (t < 2*128*384) {
        int l = t / (128*384); int rem = t - l*(128*384);
        int j = rem / 384, k = rem - j*384;
        const float* brow = Bp + (size_t)l*384*128 + (size_t)k*128;
        float v = brow[j];
        if (l == 0) {
            const float* lrow = linp + (size_t)j*128;
            float s = 0.f;
            #pragma unroll 8
            for (int m = 0; m < 128; m++) s += brow[m] * lrow[m];
            v += s;
        }
        Btp[(size_t)l*49152 + pack_off(j, k)] = f2b(v);
        return;
    }
    t -= 2*128*384;
    if (t < 2*128*256) {
        int l = t / (128*256); int rem = t - l*(128*256);
        int j = rem / 256, k = rem - j*256;
        const float* brow = Ba + (size_t)l*256*128 + (size_t)k*128;
        float v = brow[j];
        if (l == 0) {
            const float* lrow = lina + (size_t)j*128;
            float s = 0.f;
            #pragma unroll 8
            for (int m = 0; m < 128; m++) s += brow[m] * lrow[m];
            v += s;
        }
        Bta[(size_t)l*32768 + pack_off(j, k)] = f2b(v);
    }
}

// prep 3: bias' = bias @ (I + lin^T) for l=0 (pass-through l=1)
__global__ __launch_bounds__(256) void fold_bias(
    const float* __restrict__ biasp, const float* __restrict__ biasa,
    const float* __restrict__ linp, const float* __restrict__ lina,
    float* __restrict__ biasp2, float* __restrict__ biasa2)
{
    int t = blockIdx.x * 256 + threadIdx.x;   // 512 total
    if (t < 512) {
        int isa = t >> 8; int r = t & 255;
        int l = r >> 7, j = r & 127;
        const float* bsrc = isa ? biasa : biasp;
        const float* lin  = isa ? lina  : linp;
        float v = bsrc[r];
        if (l == 0) {
            float s = 0.f;
            for (int k = 0; k < 128; k++) s += bsrc[k] * lin[j*128 + k];
            v += s;
        }
        (isa ? biasa2 : biasp2)[r] = v;
    }
}

// ---------------------------------------------------------------------------
// fp32 -> bf16 conversion for BOTH inputs in one launch; 4 elems/thread.
__global__ __launch_bounds__(256) void to_bf16_all(
    const float* __restrict__ xp, const float* __restrict__ xa,
    ushort* __restrict__ yp, ushort* __restrict__ ya)
{
    int i = blockIdx.x * 256 + threadIdx.x;
    const int n4p = NPAPER * DIM / 4;
    const int n4a = NAUTH  * DIM / 4;
    const float* x; ushort* y;
    if (i < n4p) { x = xp; y = yp; }
    else if (i < n4p + n4a) { x = xa; y = ya; i -= n4p; }
    else return;
    float4 v = ((const float4*)x)[i];
    uint2 o;
    o.x = (uint)f2b(v.x) | ((uint)f2b(v.y) << 16);
    o.y = (uint)f2b(v.z) | ((uint)f2b(v.w) << 16);
    ((uint2*)y)[i] = o;
}

// ---------------------------------------------------------------------------
// Consolidated CSR build over the concatenated node space
//   [papers(C) | papers(W) | authors(R)]  -> rowAll[NTOT+1], colAll[3*NEDGE]
__global__ __launch_bounds__(256) void deg_count3(
    const int* __restrict__ eiC, const int* __restrict__ eiW,
    const int* __restrict__ eiR, int* __restrict__ deg)
{
    int i = blockIdx.x * 256 + threadIdx.x;
    if (i >= 3*NEDGE) return;
    int tpe = i / NEDGE, e = i - tpe*NEDGE;
    const int* ei = (tpe == 0) ? eiC : ((tpe == 1) ? eiW : eiR);
    int base = (tpe == 0) ? 0 : ((tpe == 1) ? NPAPER : 2*NPAPER);
    atomicAdd(&deg[base + ei[NEDGE + e]], 1);
}

__global__ __launch_bounds__(256) void scan_pass1(const int* __restrict__ in, int n,
                                                  int* __restrict__ out,
                                                  int* __restrict__ bsum)
{
    __shared__ int lds[256];
    int b0 = blockIdx.x * 1024;
    int t  = threadIdx.x;
    int v[4]; int s = 0;
    #pragma unroll
    for (int i = 0; i < 4; i++) {
        int idx = b0 + t*4 + i;
        v[i] = (idx < n) ? in[idx] : 0;
        s += v[i];
    }
    lds[t] = s;
    __syncthreads();
    for (int o = 1; o < 256; o <<= 1) {
        int x = (t >= o) ? lds[t - o] : 0;
        __syncthreads();
        lds[t] += x;
        __syncthreads();
    }
    int run = (t > 0) ? lds[t-1] : 0;
    if (t == 255) bsum[blockIdx.x] = lds[255];
    #pragma unroll
    for (int i = 0; i < 4; i++) {
        int idx = b0 + t*4 + i;
        if (idx < n) out[idx] = run;
        run += v[i];
    }
}

__global__ __launch_bounds__(256) void scan_pass2(int* __restrict__ bsum, int nb)
{
    __shared__ int lds[256];
    int t = threadIdx.x;
    lds[t] = (t < nb) ? bsum[t] : 0;
    __syncthreads();
    for (int o = 1; o < 256; o <<= 1) {
        int x = (t >= o) ? lds[t - o] : 0;
        __syncthreads();
        lds[t] += x;
        __syncthreads();
    }
    if (t < nb) bsum[t] = (t > 0) ? lds[t-1] : 0;
}

__global__ __launch_bounds__(256) void scan_pass3(int* __restrict__ out, int n,
                                                  const int* __restrict__ bsum,
                                                  int* __restrict__ cursor)
{
    int i = blockIdx.x * 256 + threadIdx.x;
    if (i < n) {
        int v = out[i] + bsum[i >> 10];
        out[i] = v;
        cursor[i] = v;
    }
    if (i == n) out[n] = 3*NEDGE;
}

__global__ __launch_bounds__(256) void csr_fill3(
    const int* __restrict__ eiC, const int* __restrict__ eiW,
    const int* __restrict__ eiR, int* __restrict__ cursor,
    int* __restrict__ col)
{
    int i = blockIdx.x * 256 + threadIdx.x;
    if (i >= 3*NEDGE) return;
    int tpe = i / NEDGE, e = i - tpe*NEDGE;
    const int* ei = (tpe == 0) ? eiC : ((tpe == 1) ? eiW : eiR);
    int base = (tpe == 0) ? 0 : ((tpe == 1) ? NPAPER : 2*NPAPER);
    int slot = atomicAdd(&cursor[base + ei[NEDGE + e]], 1);
    col[slot] = ei[e];
}

// ---------------------------------------------------------------------------
// Fused GATHER-MEAN + MFMA GEMM + bias + LayerNorm + ReLU.  bf16 in/out.
// Block: 256 thr (4 waves), 128 rows, full N=128 output, K = nseg*128.
// Segments: [gather(gsrc0,gbase0)] [gather(gsrc1,gbase1) if gsrc1] [self].
// A enters LDS via reg-gather + ds_write in fragment order; B staged linearly
// (pre-packed) via global_load_lds.  All frag reads ds_read_b128, conflict-free.
__global__ __launch_bounds__(256) void gemm_gather_ln(
    const ushort* __restrict__ gsrc0, int gbase0,
    const ushort* __restrict__ gsrc1, int gbase1,
    const ushort* __restrict__ xself, int N,
    const int* __restrict__ rowAll, const int* __restrict__ colAll,
    const ushort* __restrict__ Bt,
    const float* __restrict__ bias,
    const float* __restrict__ lng, const float* __restrict__ lnb,
    ushort* __restrict__ out)
{
    __shared__ ushort As[16384];  // 32KB: [kst2(2)][ks(2)][rb(8)][lane(64)][8]
    __shared__ ushort Bs[8192];   // 16KB: one K-step

    int t    = threadIdx.x;
    int w    = t >> 6;
    int lane = t & 63;
    int row0 = blockIdx.x * 128;
    int l15  = lane & 15;
    int g4v  = lane >> 4;
    int grp  = t >> 4;            // gather: node group 0..15
    int gl   = t & 15;            // gather: dim-chunk 0..15 (8 bf16 each)

    int nseg = (gsrc1 != nullptr) ? 3 : 2;

    f32x4 acc0[8], acc1[8];
    #pragma unroll
    for (int f = 0; f < 8; f++) {
        acc0[f] = (f32x4){0.f, 0.f, 0.f, 0.f};
        acc1[f] = (f32x4){0.f, 0.f, 0.f, 0.f};
    }

    for (int seg = 0; seg < nseg; seg++) {
        bool isself = (seg == nseg - 1);
        // ---- fill As (fragment layout) for this 128-dim segment ----
        if (!isself) {
            const ushort* xs = (seg == 0) ? gsrc0 : gsrc1;
            int gbase = (seg == 0) ? gbase0 : gbase1;
            for (int bat = 0; bat < 8; bat++) {
                int r = bat*16 + grp;
                int node = row0 + r; node = (node < N) ? node : (N - 1);
                int s = rowAll[gbase + node], e = rowAll[gbase + node + 1];
                float a[8] = {0,0,0,0,0,0,0,0};
                float b[8] = {0,0,0,0,0,0,0,0};
                int j = s;
                for (; j + 2 <= e; j += 2) {
                    int s0 = colAll[j], s1 = colAll[j+1];
                    uint4 v0 = *(const uint4*)(xs + (size_t)s0*DIM + gl*8);
                    uint4 v1 = *(const uint4*)(xs + (size_t)s1*DIM + gl*8);
                    a[0] += b2f(v0.x & 0xffffu); a[1] += b2f(v0.x >> 16);
                    a[2] += b2f(v0.y & 0xffffu); a[3] += b2f(v0.y >> 16);
                    a[4] += b2f(v0.z & 0xffffu); a[5] += b2f(v0.z >> 16);
                    a[6] += b2f(v0.w & 0xffffu); a[7] += b2f(v0.w >> 16);
                    b[0] += b2f(v1.x & 0xffffu); b[1] += b2f(v1.x >> 16);
                    b[2] += b2f(v1.y & 0xffffu); b[3] += b2f(v1.y >> 16);
                    b[4] += b2f(v1.z & 0xffffu); b[5] += b2f(v1.z >> 16);
                    b[6] += b2f(v1.w & 0xffffu); b[7] += b2f(v1.w >> 16);
                }
                if (j < e) {
                    uint4 v0 = *(const uint4*)(xs + (size_t)colAll[j]*DIM + gl*8);
                    a[0] += b2f(v0.x & 0xffffu); a[1] += b2f(v0.x >> 16);
                    a[2] += b2f(v0.y & 0xffffu); a[3] += b2f(v0.y >> 16);
                    a[4] += b2f(v0.z & 0xffffu); a[5] += b2f(v0.z >> 16);
                    a[6] += b2f(v0.w & 0xffffu); a[7] += b2f(v0.w >> 16);
                }
                float inv = (e > s) ? 1.f / (float)(e - s) : 0.f;
                uint4 o;
                o.x = (uint)f2b((a[0]+b[0])*inv) | ((uint)f2b((a[1]+b[1])*inv) << 16);
                o.y = (uint)f2b((a[2]+b[2])*inv) | ((uint)f2b((a[3]+b[3])*inv) << 16);
                o.z = (uint)f2b((a[4]+b[4])*inv) | ((uint)f2b((a[5]+b[5])*inv) << 16);
                o.w = (uint)f2b((a[6]+b[6])*inv) | ((uint)f2b((a[7]+b[7])*inv) << 16);
                int kst2 = gl >> 3, ks = (gl >> 2) & 1, g4 = gl & 3;
                *(uint4*)(&As[(((kst2*2 + ks)*8 + (r >> 4))*64 + (g4*16 + (r & 15)))*8]) = o;
            }
        } else {
            for (int bat = 0; bat < 8; bat++) {
                int r = bat*16 + grp;
                int node = row0 + r; node = (node < N) ? node : (N - 1);
                uint4 v = *(const uint4*)(xself + (size_t)node*DIM + gl*8);
                int kst2 = gl >> 3, ks = (gl >> 2) & 1, g4 = gl & 3;
                *(uint4*)(&As[(((kst2*2 + ks)*8 + (r >> 4))*64 + (g4*16 + (r & 15)))*8]) = v;
            }
        }

        #pragma unroll
        for (int kst2 = 0; kst2 < 2; kst2++) {
            // stage Bs: linear 16KB copy of K-step (seg*2 + kst2) from packed Bt.
            #pragma unroll
            for (int p = 0; p < 4; p++) {
                int q = p*256 + t;
                int qbase = p*256 + w*64;
                GLD_LDS16(Bt + ((size_t)(seg*2 + kst2)*8192 + (size_t)q*8), Bs + qbase*8);
            }
            __syncthreads();
            #pragma unroll
            for (int ks = 0; ks < 2; ks++) {
                short8 a0 = *(const short8*)(&As[(((kst2*2+ks)*8 + w*2 + 0)*64 + lane)*8]);
                short8 a1 = *(const short8*)(&As[(((kst2*2+ks)*8 + w*2 + 1)*64 + lane)*8]);
                #pragma unroll
                for (int f = 0; f < 8; f++) {
                    short8 bv = *(const short8*)(&Bs[((ks*8 + f)*64 + lane)*8]);
                    acc0[f] = __builtin_amdgcn_mfma_f32_16x16x32_bf16(a0, bv, acc0[f], 0, 0, 0);
                    acc1[f] = __builtin_amdgcn_mfma_f32_16x16x32_bf16(a1, bv, acc1[f], 0, 0, 0);
                }
            }
            __syncthreads();
        }
    }

    // epilogue: bias + LN + ReLU + bf16 store.
    float bv[8], gv[8], bbv[8];
    #pragma unroll
    for (int f = 0; f < 8; f++) {
        bv[f]  = bias[f*16 + l15];
        gv[f]  = lng [f*16 + l15];
        bbv[f] = lnb [f*16 + l15];
    }
    #pragma unroll
    for (int r2 = 0; r2 < 2; r2++) {
        #pragma unroll
        for (int i = 0; i < 4; i++) {
            int grow = row0 + w*32 + r2*16 + g4v*4 + i;
            float vv[8];
            float s = 0.f, sq = 0.f;
            #pragma unroll
            for (int f = 0; f < 8; f++) {
                float av = r2 ? acc1[f][i] : acc0[f][i];
                vv[f] = av + bv[f];
                s  += vv[f];
                sq += vv[f] * vv[f];
            }
            s += __shfl_xor(s, 1);  sq += __shfl_xor(sq, 1);
            s += __shfl_xor(s, 2);  sq += __shfl_xor(sq, 2);
            s += __shfl_xor(s, 4);  sq += __shfl_xor(sq, 4);
            s += __shfl_xor(s, 8);  sq += __shfl_xor(sq, 8);
            float m   = s * (1.f/128.f);
            float var = sq * (1.f/128.f) - m*m;
            float rr  = rsqrtf(var + 1e-5f);
            if (grow < N) {
                #pragma unroll
                for (int f = 0; f < 8; f++) {
                    float y = (vv[f] - m) * rr * gv[f] + bbv[f];
                    y = fmaxf(y, 0.f);
                    out[(size_t)grow*DIM + f*16 + l15] = f2b(y);
                }
            }
        }
    }
}

// ---------------------------------------------------------------------------
// Head: out[N][16] = xp(bf16)[N][128] @ Wh[128][16] + bh.  16 rows/block.
__global__ __launch_bounds__(256) void head_kernel(
    const ushort* __restrict__ xp, const float* __restrict__ Wh,
    const float* __restrict__ bh, float* __restrict__ out)
{
    __shared__ float Xs[16*128];
    __shared__ float Ws[128*16];
    int t = threadIdx.x;
    int row0 = blockIdx.x * 16;
    for (int i = t; i < 2048; i += 256) Ws[i] = Wh[i];
    {
        int r = t >> 4, k8 = (t & 15) * 8;
        int gr = row0 + r;
        if (gr < NPAPER) {
            uint4 v = *(const uint4*)(xp + (size_t)gr*DIM + k8);
            const ushort* pv = (const ushort*)&v;
            #pragma unroll
            for (int i = 0; i < 8; i++) Xs[r*128 + k8 + i] = b2f(pv[i]);
        } else {
            #pragma unroll
            for (int i = 0; i < 8; i++) Xs[r*128 + k8 + i] = 0.f;
        }
    }
    __syncthreads();
    int r = t >> 4, c = t & 15;
    float acc = bh[c];
    #pragma unroll 16
    for (int k = 0; k < 128; k++) acc += Xs[r*128 + k] * Ws[k*16 + c];
    int gr = row0 + r;
    if (gr < NPAPER) out[(size_t)gr*NCLS + c] = acc;
}

// ---------------------------------------------------------------------------
extern "C" void kernel_launch(void* const* d_in, const int* in_sizes, int n_in,
                              void* d_out, int out_size, void* d_ws, size_t ws_size,
                              hipStream_t stream)
{
    const float* x_paper  = (const float*)d_in[0];
    const float* x_author = (const float*)d_in[1];
    const int*   ei_cites = (const int*)d_in[2];
    const int*   ei_writes= (const int*)d_in[3];
    const int*   ei_rev   = (const int*)d_in[4];
    const float* Wl       = (const float*)d_in[5];
    const float* Wr       = (const float*)d_in[6];
    const float* bl       = (const float*)d_in[7];
    const float* linp     = (const float*)d_in[8];
    const float* lina     = (const float*)d_in[9];
    const float* ln_s     = (const float*)d_in[10];
    const float* ln_b     = (const float*)d_in[11];
    const float* Wh       = (const float*)d_in[12];
    const float* bh       = (const float*)d_in[13];
    float* out = (float*)d_out;

    float* ws = (float*)d_ws;
    size_t off = 0;
    float* Bp     = ws + off; off += 2*384*128;
    float* Ba     = ws + off; off += 2*256*128;
    float* biasp  = ws + off; off += 2*128;
    float* biasa  = ws + off; off += 2*128;
    float* biasp2 = ws + off; off += 2*128;
    float* biasa2 = ws + off; off += 2*128;

    ushort* uws = (ushort*)(ws + off);
    size_t uoff = 0;
    ushort* xpb0 = uws + uoff; uoff += (size_t)NPAPER * DIM;
    ushort* xab0 = uws + uoff; uoff += (size_t)NAUTH  * DIM;
    ushort* xpb1 = uws + uoff; uoff += (size_t)NPAPER * DIM;
    ushort* xab1 = uws + uoff; uoff += (size_t)NAUTH  * DIM;
    ushort* Btp  = uws + uoff; uoff += 2*49152;
    ushort* Bta  = uws + uoff; uoff += 2*32768;
    if (uoff & 1) uoff++;

    int* iws = (int*)(uws + uoff);
    size_t ioff = 0;
    int* rowAll = iws + ioff; ioff += NTOT + 1;
    int* cursor = iws + ioff; ioff += NTOT;
    int* deg    = iws + ioff; ioff += NTOT;
    int* colAll = iws + ioff; ioff += 3*NEDGE;
    int* bsum   = iws + ioff; ioff += 256;

    // ---- weight prep ----
    prep_weights<<<(2*384*128 + 2*256*128 + 512 + 255)/256, 256, 0, stream>>>(
        Wl, Wr, bl, Bp, Ba, biasp, biasa);
    build_bt<<<(2*128*384 + 2*128*256 + 255)/256, 256, 0, stream>>>(
        Bp, Ba, linp, lina, Btp, Bta);
    fold_bias<<<2, 256, 0, stream>>>(biasp, biasa, linp, lina, biasp2, biasa2);

    // ---- input conversion to bf16 (single launch) ----
    to_bf16_all<<<((NPAPER + NAUTH)*DIM/4 + 255)/256, 256, 0, stream>>>(
        x_paper, x_author, xpb0, xab0);

    // ---- consolidated CSR build ----
    hipMemsetAsync(deg, 0, (size_t)NTOT * 4, stream);
    deg_count3<<<(3*NEDGE + 255)/256, 256, 0, stream>>>(ei_cites, ei_writes, ei_rev, deg);
    {
        int nb = (NTOT + 1023) / 1024;   // 245 <= 256
        scan_pass1<<<nb, 256, 0, stream>>>(deg, NTOT, rowAll, bsum);
        scan_pass2<<<1, 256, 0, stream>>>(bsum, nb);
        scan_pass3<<<(NTOT + 256)/256 + 1, 256, 0, stream>>>(rowAll, NTOT, bsum, cursor);
    }
    csr_fill3<<<(3*NEDGE + 255)/256, 256, 0, stream>>>(ei_cites, ei_writes, ei_rev,
                                                       cursor, colAll);

    // ---- 2 layers, ping-pong activations ----
    for (int l = 0; l < 2; l++) {
        const ushort* inp  = l ? xpb1 : xpb0;
        const ushort* ina  = l ? xab1 : xab0;
        ushort*       outp = l ? xpb0 : xpb1;
        ushort*       outa = l ? xab0 : xab1;

        // paper: segs = [gather C (src=paper) | gather W (src=author) | self p]
        gemm_gather_ln<<<(NPAPER + 127)/128, 256, 0, stream>>>(
            inp, 0, ina, NPAPER, inp, NPAPER,
            rowAll, colAll, Btp + (size_t)l*49152, biasp2 + l*128,
            ln_s + (l*2+0)*128, ln_b + (l*2+0)*128, outp);
        // author: segs = [gather R (src=paper) | self a]
        gemm_gather_ln<<<(NAUTH + 127)/128, 256, 0, stream>>>(
            inp, 2*NPAPER, nullptr, 0, ina, NAUTH,
            rowAll, colAll, Bta + (size_t)l*32768, biasa2 + l*128,
            ln_s + (l*2+1)*128, ln_b + (l*2+1)*128, outa);
    }

    // l=1 paper output landed in xpb0
    head_kernel<<<(NPAPER + 15)/16, 256, 0, stream>>>(xpb0, Wh, bh, out);
}

// Round 6
// 445.463 us; speedup vs baseline: 1.4245x; 1.4245x over previous
//
#include <hip/hip_runtime.h>
#include <math.h>

#define NPAPER 100000
#define NAUTH  50000
#define DIM    128
#define NEDGE  500000
#define NCLS   16
#define NTOT   (2*NPAPER + NAUTH)   // concatenated CSR node space (C | W | R)

typedef unsigned int   uint;
typedef unsigned short ushort;
using short8 = __attribute__((ext_vector_type(8))) short;
using f32x4  = __attribute__((ext_vector_type(4))) float;

__device__ __forceinline__ float b2f(uint u) {
    return __uint_as_float(u << 16);
}
__device__ __forceinline__ ushort f2b(float f) {   // round-to-nearest-even
    uint x = __float_as_uint(f);
    return (ushort)((x + 0x7fffu + ((x >> 16) & 1u)) >> 16);
}

// global_load_lds: linear LDS dest (wave base + lane*16), per-lane global src.
#define GLD_LDS16(srcp, ldsp) \
    __builtin_amdgcn_global_load_lds( \
        (const __attribute__((address_space(1))) void*)(srcp), \
        (__attribute__((address_space(3))) void*)(ldsp), 16, 0, 0)

// ---------------------------------------------------------------------------
// prep 1: Bp[l]: [384][128] k-major f32 = [Wl0^T; Wl1^T; (Wr0+Wr1)^T]
//         Ba[l]: [256][128] = [Wl2^T; Wr2^T];  biasp/biasa
__global__ __launch_bounds__(256) void prep_weights(
    const float* __restrict__ Wl, const float* __restrict__ Wr,
    const float* __restrict__ bl,
    float* __restrict__ Bp, float* __restrict__ Ba,
    float* __restrict__ biasp, float* __restrict__ biasa)
{
    int t = blockIdx.x * 256 + threadIdx.x;
    if (t < 2*384*128) {
        int l = t / (384*128); int rem = t - l*(384*128);
        int k = rem >> 7, j = rem & 127;
        float v;
        if (k < 128)      v = Wl[((l*3+0)*128 + j)*128 + k];
        else if (k < 256) v = Wl[((l*3+1)*128 + j)*128 + (k-128)];
        else              v = Wr[((l*3+0)*128 + j)*128 + (k-256)]
                            + Wr[((l*3+1)*128 + j)*128 + (k-256)];
        Bp[t] = v;
        return;
    }
    t -= 2*384*128;
    if (t < 2*256*128) {
        int l = t / (256*128); int rem = t - l*(256*128);
        int k = rem >> 7, j = rem & 127;
        Ba[t] = (k < 128) ? Wl[((l*3+2)*128 + j)*128 + k]
                          : Wr[((l*3+2)*128 + j)*128 + (k-128)];
        return;
    }
    t -= 2*256*128;
    if (t < 256) { int l=t>>7, j=t&127; biasp[t] = bl[(l*3+0)*128+j] + bl[(l*3+1)*128+j]; return; }
    t -= 256;
    if (t < 256) { int l=t>>7, j=t&127; biasa[t] = bl[(l*3+2)*128+j]; return; }
}

// prep 2: residual fold + bf16 + PACK into MFMA-fragment order.
// Per 64-k step: [ks(2)][f(8)][lane(64)][8 elems]; staging = pure linear copy.
__device__ __forceinline__ size_t pack_off(int j, int k) {
    int kstep = k >> 6, ks = (k >> 5) & 1, g4 = (k >> 3) & 3, jj = k & 7;
    int f = j >> 4, l15 = j & 15;
    return (size_t)kstep*8192 + (size_t)(ks*512 + f*64 + g4*16 + l15)*8 + jj;
}

__global__ __launch_bounds__(256) void build_bt(
    const float* __restrict__ Bp, const float* __restrict__ Ba,
    const float* __restrict__ linp, const float* __restrict__ lina,
    ushort* __restrict__ Btp, ushort* __restrict__ Bta)
{
    int t = blockIdx.x * 256 + threadIdx.x;
    if (t < 2*128*384) {
        int l = t / (128*384); int rem = t - l*(128*384);
        int j = rem / 384, k = rem - j*384;
        const float* brow = Bp + (size_t)l*384*128 + (size_t)k*128;
        float v = brow[j];
        if (l == 0) {
            const float* lrow = linp + (size_t)j*128;
            float s = 0.f;
            #pragma unroll 8
            for (int m = 0; m < 128; m++) s += brow[m] * lrow[m];
            v += s;
        }
        Btp[(size_t)l*49152 + pack_off(j, k)] = f2b(v);
        return;
    }
    t -= 2*128*384;
    if (t < 2*128*256) {
        int l = t / (128*256); int rem = t - l*(128*256);
        int j = rem / 256, k = rem - j*256;
        const float* brow = Ba + (size_t)l*256*128 + (size_t)k*128;
        float v = brow[j];
        if (l == 0) {
            const float* lrow = lina + (size_t)j*128;
            float s = 0.f;
            #pragma unroll 8
            for (int m = 0; m < 128; m++) s += brow[m] * lrow[m];
            v += s;
        }
        Bta[(size_t)l*32768 + pack_off(j, k)] = f2b(v);
    }
}

// prep 3: bias' = bias @ (I + lin^T) for l=0 (pass-through l=1)
__global__ __launch_bounds__(256) void fold_bias(
    const float* __restrict__ biasp, const float* __restrict__ biasa,
    const float* __restrict__ linp, const float* __restrict__ lina,
    float* __restrict__ biasp2, float* __restrict__ biasa2)
{
    int t = blockIdx.x * 256 + threadIdx.x;   // 512 total
    if (t < 512) {
        int isa = t >> 8; int r = t & 255;
        int l = r >> 7, j = r & 127;
        const float* bsrc = isa ? biasa : biasp;
        const float* lin  = isa ? lina  : linp;
        float v = bsrc[r];
        if (l == 0) {
            float s = 0.f;
            for (int k = 0; k < 128; k++) s += bsrc[k] * lin[j*128 + k];
            v += s;
        }
        (isa ? biasa2 : biasp2)[r] = v;
    }
}

// ---------------------------------------------------------------------------
// fp32 -> bf16 conversion for BOTH inputs in one launch; 4 elems/thread.
__global__ __launch_bounds__(256) void to_bf16_all(
    const float* __restrict__ xp, const float* __restrict__ xa,
    ushort* __restrict__ yp, ushort* __restrict__ ya)
{
    int i = blockIdx.x * 256 + threadIdx.x;
    const int n4p = NPAPER * DIM / 4;
    const int n4a = NAUTH  * DIM / 4;
    const float* x; ushort* y;
    if (i < n4p) { x = xp; y = yp; }
    else if (i < n4p + n4a) { x = xa; y = ya; i -= n4p; }
    else return;
    float4 v = ((const float4*)x)[i];
    uint2 o;
    o.x = (uint)f2b(v.x) | ((uint)f2b(v.y) << 16);
    o.y = (uint)f2b(v.z) | ((uint)f2b(v.w) << 16);
    ((uint2*)y)[i] = o;
}

// ---------------------------------------------------------------------------
// Consolidated CSR build over the concatenated node space
//   [papers(C) | papers(W) | authors(R)]  -> rowAll[NTOT+1], colAll[3*NEDGE]
__global__ __launch_bounds__(256) void deg_count3(
    const int* __restrict__ eiC, const int* __restrict__ eiW,
    const int* __restrict__ eiR, int* __restrict__ deg)
{
    int i = blockIdx.x * 256 + threadIdx.x;
    if (i >= 3*NEDGE) return;
    int tpe = i / NEDGE, e = i - tpe*NEDGE;
    const int* ei = (tpe == 0) ? eiC : ((tpe == 1) ? eiW : eiR);
    int base = (tpe == 0) ? 0 : ((tpe == 1) ? NPAPER : 2*NPAPER);
    atomicAdd(&deg[base + ei[NEDGE + e]], 1);
}

__global__ __launch_bounds__(256) void scan_pass1(const int* __restrict__ in, int n,
                                                  int* __restrict__ out,
                                                  int* __restrict__ bsum)
{
    __shared__ int lds[256];
    int b0 = blockIdx.x * 1024;
    int t  = threadIdx.x;
    int v[4]; int s = 0;
    #pragma unroll
    for (int i = 0; i < 4; i++) {
        int idx = b0 + t*4 + i;
        v[i] = (idx < n) ? in[idx] : 0;
        s += v[i];
    }
    lds[t] = s;
    __syncthreads();
    for (int o = 1; o < 256; o <<= 1) {
        int x = (t >= o) ? lds[t - o] : 0;
        __syncthreads();
        lds[t] += x;
        __syncthreads();
    }
    int run = (t > 0) ? lds[t-1] : 0;
    if (t == 255) bsum[blockIdx.x] = lds[255];
    #pragma unroll
    for (int i = 0; i < 4; i++) {
        int idx = b0 + t*4 + i;
        if (idx < n) out[idx] = run;
        run += v[i];
    }
}

__global__ __launch_bounds__(256) void scan_pass2(int* __restrict__ bsum, int nb)
{
    __shared__ int lds[256];
    int t = threadIdx.x;
    lds[t] = (t < nb) ? bsum[t] : 0;
    __syncthreads();
    for (int o = 1; o < 256; o <<= 1) {
        int x = (t >= o) ? lds[t - o] : 0;
        __syncthreads();
        lds[t] += x;
        __syncthreads();
    }
    if (t < nb) bsum[t] = (t > 0) ? lds[t-1] : 0;
}

__global__ __launch_bounds__(256) void scan_pass3(int* __restrict__ out, int n,
                                                  const int* __restrict__ bsum,
                                                  int* __restrict__ cursor)
{
    int i = blockIdx.x * 256 + threadIdx.x;
    if (i < n) {
        int v = out[i] + bsum[i >> 10];
        out[i] = v;
        cursor[i] = v;
    }
    if (i == n) out[n] = 3*NEDGE;
}

__global__ __launch_bounds__(256) void csr_fill3(
    const int* __restrict__ eiC, const int* __restrict__ eiW,
    const int* __restrict__ eiR, int* __restrict__ cursor,
    int* __restrict__ col)
{
    int i = blockIdx.x * 256 + threadIdx.x;
    if (i >= 3*NEDGE) return;
    int tpe = i / NEDGE, e = i - tpe*NEDGE;
    const int* ei = (tpe == 0) ? eiC : ((tpe == 1) ? eiW : eiR);
    int base = (tpe == 0) ? 0 : ((tpe == 1) ? NPAPER : 2*NPAPER);
    int slot = atomicAdd(&cursor[base + ei[NEDGE + e]], 1);
    col[slot] = ei[e];
}

// ---------------------------------------------------------------------------
// Gather-mean over the consolidated CSR, all 3 edge types in one launch.
// 16 lanes per node (16B/lane row chunks), 4-deep load pipeline with dual
// accumulators for latency hiding.
__device__ __forceinline__ void acc8(float* a, uint4 v) {
    a[0] += b2f(v.x & 0xffffu); a[1] += b2f(v.x >> 16);
    a[2] += b2f(v.y & 0xffffu); a[3] += b2f(v.y >> 16);
    a[4] += b2f(v.z & 0xffffu); a[5] += b2f(v.z >> 16);
    a[6] += b2f(v.w & 0xffffu); a[7] += b2f(v.w >> 16);
}

__global__ __launch_bounds__(256) void gather3(
    const ushort* __restrict__ xp, const ushort* __restrict__ xa,
    const int* __restrict__ rowAll, const int* __restrict__ colAll,
    ushort* __restrict__ aggC, ushort* __restrict__ aggW,
    ushort* __restrict__ aggR)
{
    int g    = (blockIdx.x * 256 + threadIdx.x) >> 4;
    int lane = threadIdx.x & 15;
    if (g >= NTOT) return;
    const ushort* xs; ushort* out; int node;
    if (g < NPAPER)        { node = g;            xs = xp; out = aggC; }
    else if (g < 2*NPAPER) { node = g - NPAPER;   xs = xa; out = aggW; }
    else                   { node = g - 2*NPAPER; xs = xp; out = aggR; }

    int s = rowAll[g], e = rowAll[g + 1];
    float a[8] = {0,0,0,0,0,0,0,0};
    float b[8] = {0,0,0,0,0,0,0,0};
    int j = s;
    #pragma unroll 1
    for (; j + 4 <= e; j += 4) {
        int s0 = colAll[j], s1 = colAll[j+1], s2 = colAll[j+2], s3 = colAll[j+3];
        uint4 v0 = *(const uint4*)(xs + (size_t)s0 * DIM + lane * 8);
        uint4 v1 = *(const uint4*)(xs + (size_t)s1 * DIM + lane * 8);
        uint4 v2 = *(const uint4*)(xs + (size_t)s2 * DIM + lane * 8);
        uint4 v3 = *(const uint4*)(xs + (size_t)s3 * DIM + lane * 8);
        acc8(a, v0);
        acc8(b, v1);
        acc8(a, v2);
        acc8(b, v3);
    }
    #pragma unroll 1
    for (; j < e; j++) {
        uint4 v0 = *(const uint4*)(xs + (size_t)colAll[j] * DIM + lane * 8);
        acc8(a, v0);
    }
    float inv = (e > s) ? 1.f / (float)(e - s) : 0.f;
    #pragma unroll
    for (int i = 0; i < 8; i++) a[i] = (a[i] + b[i]) * inv;
    uint4 o;
    o.x = (uint)f2b(a[0]) | ((uint)f2b(a[1]) << 16);
    o.y = (uint)f2b(a[2]) | ((uint)f2b(a[3]) << 16);
    o.z = (uint)f2b(a[4]) | ((uint)f2b(a[5]) << 16);
    o.w = (uint)f2b(a[6]) | ((uint)f2b(a[7]) << 16);
    *(uint4*)(out + (size_t)node * DIM + lane * 8) = o;
}

// ---------------------------------------------------------------------------
// Merged MFMA GEMM + bias + LayerNorm + ReLU for BOTH node types, one launch.
// Blocks [0, pblk): paper rows (K=384, segs aggC|aggW|self-p).
// Blocks [pblk, ..): author rows (K=256, segs aggR|self-a).
// Block: 256 thr (4 waves), 128 rows (wave owns 32), full N=128, K-step 64.
// LDS fragment-contiguous; A via global_load_lds w/ swizzled global source,
// B staged linearly from pre-packed Bt.  All frag reads conflict-free.
__global__ __launch_bounds__(256) void gemm_ln2(
    const ushort* __restrict__ aggC, const ushort* __restrict__ aggW,
    const ushort* __restrict__ aggR,
    const ushort* __restrict__ xp, const ushort* __restrict__ xa,
    const ushort* __restrict__ Btp, const ushort* __restrict__ Bta,
    const float* __restrict__ biasp, const float* __restrict__ biasa,
    const float* __restrict__ lns, const float* __restrict__ lnb,  // [paper|author] 2*128
    ushort* __restrict__ outp, ushort* __restrict__ outa, int pblk)
{
    __shared__ ushort As[8192];   // 16 KB, one K-step
    __shared__ ushort Bs[8192];   // 16 KB

    bool isp = (int)blockIdx.x < pblk;
    int  bid = isp ? blockIdx.x : (blockIdx.x - pblk);
    int  N   = isp ? NPAPER : NAUTH;
    int  K   = isp ? 384 : 256;
    const ushort* A0 = isp ? aggC : aggR;
    const ushort* A1 = isp ? aggW : xa;
    const ushort* A2 = isp ? xp   : xa;
    const ushort* Bt = isp ? Btp  : Bta;
    const float* bias = isp ? biasp : biasa;
    const float* lng  = lns + (isp ? 0 : 128);
    const float* lnbb = lnb + (isp ? 0 : 128);
    ushort* out = isp ? outp : outa;

    int t    = threadIdx.x;
    int w    = t >> 6;
    int lane = t & 63;
    int row0 = bid * 128;
    int l15  = lane & 15;
    int g4   = lane >> 4;

    f32x4 acc0[8], acc1[8];
    #pragma unroll
    for (int f = 0; f < 8; f++) {
        acc0[f] = (f32x4){0.f, 0.f, 0.f, 0.f};
        acc1[f] = (f32x4){0.f, 0.f, 0.f, 0.f};
    }

    int nstep = K >> 6;
    for (int st = 0; st < nstep; st++) {
        int kk  = st << 6;
        int seg = kk >> 7, kl = kk & 127;
        const ushort* Ap = (seg == 0) ? A0 : ((seg == 1) ? A1 : A2);

        // stage A: 1024 chunks of 16B in [ks][rb][lane] order.
        #pragma unroll
        for (int p = 0; p < 4; p++) {
            int q  = p*256 + t;
            int ks = q >> 9, rb = (q >> 6) & 7, l = q & 63;
            int row = row0 + rb*16 + (l & 15);
            row = (row < N) ? row : (N - 1);
            int k = kl + ks*32 + (l >> 4)*8;
            int qbase = p*256 + w*64;
            GLD_LDS16(Ap + (size_t)row*DIM + k, As + qbase*8);
        }
        // stage B: linear copy of 16 KB from packed Bt.
        #pragma unroll
        for (int p = 0; p < 4; p++) {
            int q = p*256 + t;
            int qbase = p*256 + w*64;
            GLD_LDS16(Bt + ((size_t)st*8192 + (size_t)q*8), Bs + qbase*8);
        }
        __syncthreads();

        #pragma unroll
        for (int ks = 0; ks < 2; ks++) {
            short8 a0 = *(const short8*)(&As[((ks*8 + w*2 + 0)*64 + lane)*8]);
            short8 a1 = *(const short8*)(&As[((ks*8 + w*2 + 1)*64 + lane)*8]);
            #pragma unroll
            for (int f = 0; f < 8; f++) {
                short8 bv = *(const short8*)(&Bs[((ks*8 + f)*64 + lane)*8]);
                acc0[f] = __builtin_amdgcn_mfma_f32_16x16x32_bf16(a0, bv, acc0[f], 0, 0, 0);
                acc1[f] = __builtin_amdgcn_mfma_f32_16x16x32_bf16(a1, bv, acc1[f], 0, 0, 0);
            }
        }
        __syncthreads();
    }

    // epilogue: bias + LN + ReLU + bf16 store.
    float bv[8], gv[8], bbv[8];
    #pragma unroll
    for (int f = 0; f < 8; f++) {
        bv[f]  = bias[f*16 + l15];
        gv[f]  = lng [f*16 + l15];
        bbv[f] = lnbb[f*16 + l15];
    }
    #pragma unroll
    for (int r2 = 0; r2 < 2; r2++) {
        #pragma unroll
        for (int i = 0; i < 4; i++) {
            int grow = row0 + w*32 + r2*16 + g4*4 + i;
            float vv[8];
            float s = 0.f, sq = 0.f;
            #pragma unroll
            for (int f = 0; f < 8; f++) {
                float av = r2 ? acc1[f][i] : acc0[f][i];
                vv[f] = av + bv[f];
                s  += vv[f];
                sq += vv[f] * vv[f];
            }
            s += __shfl_xor(s, 1);  sq += __shfl_xor(sq, 1);
            s += __shfl_xor(s, 2);  sq += __shfl_xor(sq, 2);
            s += __shfl_xor(s, 4);  sq += __shfl_xor(sq, 4);
            s += __shfl_xor(s, 8);  sq += __shfl_xor(sq, 8);
            float m   = s * (1.f/128.f);
            float var = sq * (1.f/128.f) - m*m;
            float rr  = rsqrtf(var + 1e-5f);
            if (grow < N) {
                #pragma unroll
                for (int f = 0; f < 8; f++) {
                    float y = (vv[f] - m) * rr * gv[f] + bbv[f];
                    y = fmaxf(y, 0.f);
                    out[(size_t)grow*DIM + f*16 + l15] = f2b(y);
                }
            }
        }
    }
}

// ---------------------------------------------------------------------------
// Head: out[N][16] = xp(bf16)[N][128] @ Wh[128][16] + bh.  16 rows/block.
__global__ __launch_bounds__(256) void head_kernel(
    const ushort* __restrict__ xp, const float* __restrict__ Wh,
    const float* __restrict__ bh, float* __restrict__ out)
{
    __shared__ float Xs[16*128];
    __shared__ float Ws[128*16];
    int t = threadIdx.x;
    int row0 = blockIdx.x * 16;
    for (int i = t; i < 2048; i += 256) Ws[i] = Wh[i];
    {
        int r = t >> 4, k8 = (t & 15) * 8;
        int gr = row0 + r;
        if (gr < NPAPER) {
            uint4 v = *(const uint4*)(xp + (size_t)gr*DIM + k8);
            const ushort* pv = (const ushort*)&v;
            #pragma unroll
            for (int i = 0; i < 8; i++) Xs[r*128 + k8 + i] = b2f(pv[i]);
        } else {
            #pragma unroll
            for (int i = 0; i < 8; i++) Xs[r*128 + k8 + i] = 0.f;
        }
    }
    __syncthreads();
    int r = t >> 4, c = t & 15;
    float acc = bh[c];
    #pragma unroll 16
    for (int k = 0; k < 128; k++) acc += Xs[r*128 + k] * Ws[k*16 + c];
    int gr = row0 + r;
    if (gr < NPAPER) out[(size_t)gr*NCLS + c] = acc;
}

// ---------------------------------------------------------------------------
extern "C" void kernel_launch(void* const* d_in, const int* in_sizes, int n_in,
                              void* d_out, int out_size, void* d_ws, size_t ws_size,
                              hipStream_t stream)
{
    const float* x_paper  = (const float*)d_in[0];
    const float* x_author = (const float*)d_in[1];
    const int*   ei_cites = (const int*)d_in[2];
    const int*   ei_writes= (const int*)d_in[3];
    const int*   ei_rev   = (const int*)d_in[4];
    const float* Wl       = (const float*)d_in[5];
    const float* Wr       = (const float*)d_in[6];
    const float* bl       = (const float*)d_in[7];
    const float* linp     = (const float*)d_in[8];
    const float* lina     = (const float*)d_in[9];
    const float* ln_s     = (const float*)d_in[10];
    const float* ln_b     = (const float*)d_in[11];
    const float* Wh       = (const float*)d_in[12];
    const float* bh       = (const float*)d_in[13];
    float* out = (float*)d_out;

    float* ws = (float*)d_ws;
    size_t off = 0;
    float* Bp     = ws + off; off += 2*384*128;
    float* Ba     = ws + off; off += 2*256*128;
    float* biasp  = ws + off; off += 2*128;
    float* biasa  = ws + off; off += 2*128;
    float* biasp2 = ws + off; off += 2*128;
    float* biasa2 = ws + off; off += 2*128;

    ushort* uws = (ushort*)(ws + off);
    size_t uoff = 0;
    ushort* xpb0 = uws + uoff; uoff += (size_t)NPAPER * DIM;
    ushort* xab0 = uws + uoff; uoff += (size_t)NAUTH  * DIM;
    ushort* xpb1 = uws + uoff; uoff += (size_t)NPAPER * DIM;
    ushort* xab1 = uws + uoff; uoff += (size_t)NAUTH  * DIM;
    ushort* aggC = uws + uoff; uoff += (size_t)NPAPER * DIM;
    ushort* aggW = uws + uoff; uoff += (size_t)NPAPER * DIM;
    ushort* aggR = uws + uoff; uoff += (size_t)NAUTH  * DIM;
    ushort* Btp  = uws + uoff; uoff += 2*49152;
    ushort* Bta  = uws + uoff; uoff += 2*32768;
    if (uoff & 1) uoff++;

    int* iws = (int*)(uws + uoff);
    size_t ioff = 0;
    int* rowAll = iws + ioff; ioff += NTOT + 1;
    int* cursor = iws + ioff; ioff += NTOT;
    int* deg    = iws + ioff; ioff += NTOT;
    int* colAll = iws + ioff; ioff += 3*NEDGE;
    int* bsum   = iws + ioff; ioff += 256;

    // ---- weight prep ----
    prep_weights<<<(2*384*128 + 2*256*128 + 512 + 255)/256, 256, 0, stream>>>(
        Wl, Wr, bl, Bp, Ba, biasp, biasa);
    build_bt<<<(2*128*384 + 2*128*256 + 255)/256, 256, 0, stream>>>(
        Bp, Ba, linp, lina, Btp, Bta);
    fold_bias<<<2, 256, 0, stream>>>(biasp, biasa, linp, lina, biasp2, biasa2);

    // ---- input conversion to bf16 (single launch) ----
    to_bf16_all<<<((NPAPER + NAUTH)*DIM/4 + 255)/256, 256, 0, stream>>>(
        x_paper, x_author, xpb0, xab0);

    // ---- consolidated CSR build ----
    hipMemsetAsync(deg, 0, (size_t)NTOT * 4, stream);
    deg_count3<<<(3*NEDGE + 255)/256, 256, 0, stream>>>(ei_cites, ei_writes, ei_rev, deg);
    {
        int nb = (NTOT + 1023) / 1024;   // 245 <= 256
        scan_pass1<<<nb, 256, 0, stream>>>(deg, NTOT, rowAll, bsum);
        scan_pass2<<<1, 256, 0, stream>>>(bsum, nb);
        scan_pass3<<<(NTOT + 256)/256 + 1, 256, 0, stream>>>(rowAll, NTOT, bsum, cursor);
    }
    csr_fill3<<<(3*NEDGE + 255)/256, 256, 0, stream>>>(ei_cites, ei_writes, ei_rev,
                                                       cursor, colAll);

    const int PBLK = (NPAPER + 127) / 128;
    const int ABLK = (NAUTH  + 127) / 128;

    // ---- 2 layers, ping-pong activations ----
    for (int l = 0; l < 2; l++) {
        const ushort* inp  = l ? xpb1 : xpb0;
        const ushort* ina  = l ? xab1 : xab0;
        ushort*       outp = l ? xpb0 : xpb1;
        ushort*       outa = l ? xab0 : xab1;

        gather3<<<NTOT*16/256, 256, 0, stream>>>(
            inp, ina, rowAll, colAll, aggC, aggW, aggR);

        gemm_ln2<<<PBLK + ABLK, 256, 0, stream>>>(
            aggC, aggW, aggR, inp, ina,
            Btp + (size_t)l*49152, Bta + (size_t)l*32768,
            biasp2 + l*128, biasa2 + l*128,
            ln_s + (size_t)l*256, ln_b + (size_t)l*256,
            outp, outa, PBLK);
    }

    // l=1 paper output landed in xpb0
    head_kernel<<<(NPAPER + 15)/16, 256, 0, stream>>>(xpb0, Wh, bh, out);
}

// Round 7
// 443.773 us; speedup vs baseline: 1.4299x; 1.0038x over previous
//
#include <hip/hip_runtime.h>
#include <math.h>

#define NPAPER 100000
#define NAUTH  50000
#define DIM    128
#define NEDGE  500000
#define NCLS   16
#define NTOT   (2*NPAPER + NAUTH)   // concatenated CSR node space (C | W | R)

typedef unsigned int   uint;
typedef unsigned short ushort;
using short8 = __attribute__((ext_vector_type(8))) short;
using f32x4  = __attribute__((ext_vector_type(4))) float;

__device__ __forceinline__ float b2f(uint u) {
    return __uint_as_float(u << 16);
}
__device__ __forceinline__ ushort f2b(float f) {   // round-to-nearest-even
    uint x = __float_as_uint(f);
    return (ushort)((x + 0x7fffu + ((x >> 16) & 1u)) >> 16);
}

// global_load_lds: linear LDS dest (wave base + lane*16), per-lane global src.
#define GLD_LDS16(srcp, ldsp) \
    __builtin_amdgcn_global_load_lds( \
        (const __attribute__((address_space(1))) void*)(srcp), \
        (__attribute__((address_space(3))) void*)(ldsp), 16, 0, 0)

// ---------------------------------------------------------------------------
// prep 1: Bp[l]: [384][128] k-major f32 = [Wl0^T; Wl1^T; (Wr0+Wr1)^T]
//         Ba[l]: [256][128] = [Wl2^T; Wr2^T];  biasp/biasa
__global__ __launch_bounds__(256) void prep_weights(
    const float* __restrict__ Wl, const float* __restrict__ Wr,
    const float* __restrict__ bl,
    float* __restrict__ Bp, float* __restrict__ Ba,
    float* __restrict__ biasp, float* __restrict__ biasa)
{
    int t = blockIdx.x * 256 + threadIdx.x;
    if (t < 2*384*128) {
        int l = t / (384*128); int rem = t - l*(384*128);
        int k = rem >> 7, j = rem & 127;
        float v;
        if (k < 128)      v = Wl[((l*3+0)*128 + j)*128 + k];
        else if (k < 256) v = Wl[((l*3+1)*128 + j)*128 + (k-128)];
        else              v = Wr[((l*3+0)*128 + j)*128 + (k-256)]
                            + Wr[((l*3+1)*128 + j)*128 + (k-256)];
        Bp[t] = v;
        return;
    }
    t -= 2*384*128;
    if (t < 2*256*128) {
        int l = t / (256*128); int rem = t - l*(256*128);
        int k = rem >> 7, j = rem & 127;
        Ba[t] = (k < 128) ? Wl[((l*3+2)*128 + j)*128 + k]
                          : Wr[((l*3+2)*128 + j)*128 + (k-128)];
        return;
    }
    t -= 2*256*128;
    if (t < 256) { int l=t>>7, j=t&127; biasp[t] = bl[(l*3+0)*128+j] + bl[(l*3+1)*128+j]; return; }
    t -= 256;
    if (t < 256) { int l=t>>7, j=t&127; biasa[t] = bl[(l*3+2)*128+j]; return; }
}

// prep 2: residual fold + bf16 + PACK into MFMA-fragment order.
// Per 64-k step: [ks(2)][f(8)][lane(64)][8 elems]; staging = pure linear copy.
__device__ __forceinline__ size_t pack_off(int j, int k) {
    int kstep = k >> 6, ks = (k >> 5) & 1, g4 = (k >> 3) & 3, jj = k & 7;
    int f = j >> 4, l15 = j & 15;
    return (size_t)kstep*8192 + (size_t)(ks*512 + f*64 + g4*16 + l15)*8 + jj;
}

__global__ __launch_bounds__(256) void build_bt(
    const float* __restrict__ Bp, const float* __restrict__ Ba,
    const float* __restrict__ linp, const float* __restrict__ lina,
    ushort* __restrict__ Btp, ushort* __restrict__ Bta)
{
    int t = blockIdx.x * 256 + threadIdx.x;
    if (t < 2*128*384) {
        int l = t / (128*384); int rem = t - l*(128*384);
        int j = rem / 384, k = rem - j*384;
        const float* brow = Bp + (size_t)l*384*128 + (size_t)k*128;
        float v = brow[j];
        if (l == 0) {
            const float* lrow = linp + (size_t)j*128;
            float s = 0.f;
            #pragma unroll 8
            for (int m = 0; m < 128; m++) s += brow[m] * lrow[m];
            v += s;
        }
        Btp[(size_t)l*49152 + pack_off(j, k)] = f2b(v);
        return;
    }
    t -= 2*128*384;
    if (t < 2*128*256) {
        int l = t / (128*256); int rem = t - l*(128*256);
        int j = rem / 256, k = rem - j*256;
        const float* brow = Ba + (size_t)l*256*128 + (size_t)k*128;
        float v = brow[j];
        if (l == 0) {
            const float* lrow = lina + (size_t)j*128;
            float s = 0.f;
            #pragma unroll 8
            for (int m = 0; m < 128; m++) s += brow[m] * lrow[m];
            v += s;
        }
        Bta[(size_t)l*32768 + pack_off(j, k)] = f2b(v);
    }
}

// prep 3: bias' = bias @ (I + lin^T) for l=0 (pass-through l=1)
__global__ __launch_bounds__(256) void fold_bias(
    const float* __restrict__ biasp, const float* __restrict__ biasa,
    const float* __restrict__ linp, const float* __restrict__ lina,
    float* __restrict__ biasp2, float* __restrict__ biasa2)
{
    int t = blockIdx.x * 256 + threadIdx.x;   // 512 total
    if (t < 512) {
        int isa = t >> 8; int r = t & 255;
        int l = r >> 7, j = r & 127;
        const float* bsrc = isa ? biasa : biasp;
        const float* lin  = isa ? lina  : linp;
        float v = bsrc[r];
        if (l == 0) {
            float s = 0.f;
            for (int k = 0; k < 128; k++) s += bsrc[k] * lin[j*128 + k];
            v += s;
        }
        (isa ? biasa2 : biasp2)[r] = v;
    }
}

// ---------------------------------------------------------------------------
// fp32 -> bf16 conversion for BOTH inputs in one launch; 4 elems/thread.
__global__ __launch_bounds__(256) void to_bf16_all(
    const float* __restrict__ xp, const float* __restrict__ xa,
    ushort* __restrict__ yp, ushort* __restrict__ ya)
{
    int i = blockIdx.x * 256 + threadIdx.x;
    const int n4p = NPAPER * DIM / 4;
    const int n4a = NAUTH  * DIM / 4;
    const float* x; ushort* y;
    if (i < n4p) { x = xp; y = yp; }
    else if (i < n4p + n4a) { x = xa; y = ya; i -= n4p; }
    else return;
    float4 v = ((const float4*)x)[i];
    uint2 o;
    o.x = (uint)f2b(v.x) | ((uint)f2b(v.y) << 16);
    o.y = (uint)f2b(v.z) | ((uint)f2b(v.w) << 16);
    ((uint2*)y)[i] = o;
}

// ---------------------------------------------------------------------------
// Consolidated CSR build over the concatenated node space
//   [papers(C) | papers(W) | authors(R)]  -> rowAll[NTOT+1], colAll[3*NEDGE]
__global__ __launch_bounds__(256) void deg_count3(
    const int* __restrict__ eiC, const int* __restrict__ eiW,
    const int* __restrict__ eiR, int* __restrict__ deg)
{
    int i = blockIdx.x * 256 + threadIdx.x;
    if (i >= 3*NEDGE) return;
    int tpe = i / NEDGE, e = i - tpe*NEDGE;
    const int* ei = (tpe == 0) ? eiC : ((tpe == 1) ? eiW : eiR);
    int base = (tpe == 0) ? 0 : ((tpe == 1) ? NPAPER : 2*NPAPER);
    atomicAdd(&deg[base + ei[NEDGE + e]], 1);
}

__global__ __launch_bounds__(256) void scan_pass1(const int* __restrict__ in, int n,
                                                  int* __restrict__ out,
                                                  int* __restrict__ bsum)
{
    __shared__ int lds[256];
    int b0 = blockIdx.x * 1024;
    int t  = threadIdx.x;
    int v[4]; int s = 0;
    #pragma unroll
    for (int i = 0; i < 4; i++) {
        int idx = b0 + t*4 + i;
        v[i] = (idx < n) ? in[idx] : 0;
        s += v[i];
    }
    lds[t] = s;
    __syncthreads();
    for (int o = 1; o < 256; o <<= 1) {
        int x = (t >= o) ? lds[t - o] : 0;
        __syncthreads();
        lds[t] += x;
        __syncthreads();
    }
    int run = (t > 0) ? lds[t-1] : 0;
    if (t == 255) bsum[blockIdx.x] = lds[255];
    #pragma unroll
    for (int i = 0; i < 4; i++) {
        int idx = b0 + t*4 + i;
        if (idx < n) out[idx] = run;
        run += v[i];
    }
}

__global__ __launch_bounds__(256) void scan_pass2(int* __restrict__ bsum, int nb)
{
    __shared__ int lds[256];
    int t = threadIdx.x;
    lds[t] = (t < nb) ? bsum[t] : 0;
    __syncthreads();
    for (int o = 1; o < 256; o <<= 1) {
        int x = (t >= o) ? lds[t - o] : 0;
        __syncthreads();
        lds[t] += x;
        __syncthreads();
    }
    if (t < nb) bsum[t] = (t > 0) ? lds[t-1] : 0;
}

__global__ __launch_bounds__(256) void scan_pass3(int* __restrict__ out, int n,
                                                  const int* __restrict__ bsum,
                                                  int* __restrict__ cursor)
{
    int i = blockIdx.x * 256 + threadIdx.x;
    if (i < n) {
        int v = out[i] + bsum[i >> 10];
        out[i] = v;
        cursor[i] = v;
    }
    if (i == n) out[n] = 3*NEDGE;
}

__global__ __launch_bounds__(256) void csr_fill3(
    const int* __restrict__ eiC, const int* __restrict__ eiW,
    const int* __restrict__ eiR, int* __restrict__ cursor,
    int* __restrict__ col)
{
    int i = blockIdx.x * 256 + threadIdx.x;
    if (i >= 3*NEDGE) return;
    int tpe = i / NEDGE, e = i - tpe*NEDGE;
    const int* ei = (tpe == 0) ? eiC : ((tpe == 1) ? eiW : eiR);
    int base = (tpe == 0) ? 0 : ((tpe == 1) ? NPAPER : 2*NPAPER);
    int slot = atomicAdd(&cursor[base + ei[NEDGE + e]], 1);
    col[slot] = ei[e];
}

// ---------------------------------------------------------------------------
// Gather-mean over the consolidated CSR, all 3 edge types in one launch.
// 16 lanes per node (16B/lane row chunks), 4-deep load pipeline with dual
// accumulators for latency hiding.
__device__ __forceinline__ void acc8(float* a, uint4 v) {
    a[0] += b2f(v.x & 0xffffu); a[1] += b2f(v.x >> 16);
    a[2] += b2f(v.y & 0xffffu); a[3] += b2f(v.y >> 16);
    a[4] += b2f(v.z & 0xffffu); a[5] += b2f(v.z >> 16);
    a[6] += b2f(v.w & 0xffffu); a[7] += b2f(v.w >> 16);
}

__global__ __launch_bounds__(256) void gather3(
    const ushort* __restrict__ xp, const ushort* __restrict__ xa,
    const int* __restrict__ rowAll, const int* __restrict__ colAll,
    ushort* __restrict__ aggC, ushort* __restrict__ aggW,
    ushort* __restrict__ aggR)
{
    int g    = (blockIdx.x * 256 + threadIdx.x) >> 4;
    int lane = threadIdx.x & 15;
    if (g >= NTOT) return;
    const ushort* xs; ushort* out; int node;
    if (g < NPAPER)        { node = g;            xs = xp; out = aggC; }
    else if (g < 2*NPAPER) { node = g - NPAPER;   xs = xa; out = aggW; }
    else                   { node = g - 2*NPAPER; xs = xp; out = aggR; }

    int s = rowAll[g], e = rowAll[g + 1];
    float a[8] = {0,0,0,0,0,0,0,0};
    float b[8] = {0,0,0,0,0,0,0,0};
    int j = s;
    #pragma unroll 1
    for (; j + 4 <= e; j += 4) {
        int s0 = colAll[j], s1 = colAll[j+1], s2 = colAll[j+2], s3 = colAll[j+3];
        uint4 v0 = *(const uint4*)(xs + (size_t)s0 * DIM + lane * 8);
        uint4 v1 = *(const uint4*)(xs + (size_t)s1 * DIM + lane * 8);
        uint4 v2 = *(const uint4*)(xs + (size_t)s2 * DIM + lane * 8);
        uint4 v3 = *(const uint4*)(xs + (size_t)s3 * DIM + lane * 8);
        acc8(a, v0);
        acc8(b, v1);
        acc8(a, v2);
        acc8(b, v3);
    }
    #pragma unroll 1
    for (; j < e; j++) {
        uint4 v0 = *(const uint4*)(xs + (size_t)colAll[j] * DIM + lane * 8);
        acc8(a, v0);
    }
    float inv = (e > s) ? 1.f / (float)(e - s) : 0.f;
    #pragma unroll
    for (int i = 0; i < 8; i++) a[i] = (a[i] + b[i]) * inv;
    uint4 o;
    o.x = (uint)f2b(a[0]) | ((uint)f2b(a[1]) << 16);
    o.y = (uint)f2b(a[2]) | ((uint)f2b(a[3]) << 16);
    o.z = (uint)f2b(a[4]) | ((uint)f2b(a[5]) << 16);
    o.w = (uint)f2b(a[6]) | ((uint)f2b(a[7]) << 16);
    *(uint4*)(out + (size_t)node * DIM + lane * 8) = o;
}

// ---------------------------------------------------------------------------
// Merged MFMA GEMM + bias + LayerNorm + ReLU for BOTH node types, one launch.
// Blocks [0, pblk): paper rows (K=384, segs aggC|aggW|self-p).
// Blocks [pblk, ..): author rows (K=256, segs aggR|self-a).
// Block: 256 thr (4 waves), 128 rows (wave owns 32), full N=128, K-step 64.
// LDS fragment-contiguous; A via global_load_lds w/ swizzled global source,
// B staged linearly from pre-packed Bt.  All frag reads conflict-free.
__global__ __launch_bounds__(256) void gemm_ln2(
    const ushort* __restrict__ aggC, const ushort* __restrict__ aggW,
    const ushort* __restrict__ aggR,
    const ushort* __restrict__ xp, const ushort* __restrict__ xa,
    const ushort* __restrict__ Btp, const ushort* __restrict__ Bta,
    const float* __restrict__ biasp, const float* __restrict__ biasa,
    const float* __restrict__ lns, const float* __restrict__ lnb,  // [paper|author] 2*128
    ushort* __restrict__ outp, ushort* __restrict__ outa, int pblk)
{
    __shared__ ushort As[8192];   // 16 KB, one K-step
    __shared__ ushort Bs[8192];   // 16 KB

    bool isp = (int)blockIdx.x < pblk;
    int  bid = isp ? blockIdx.x : (blockIdx.x - pblk);
    int  N   = isp ? NPAPER : NAUTH;
    int  K   = isp ? 384 : 256;
    const ushort* A0 = isp ? aggC : aggR;
    const ushort* A1 = isp ? aggW : xa;
    const ushort* A2 = isp ? xp   : xa;
    const ushort* Bt = isp ? Btp  : Bta;
    const float* bias = isp ? biasp : biasa;
    const float* lng  = lns + (isp ? 0 : 128);
    const float* lnbb = lnb + (isp ? 0 : 128);
    ushort* out = isp ? outp : outa;

    int t    = threadIdx.x;
    int w    = t >> 6;
    int lane = t & 63;
    int row0 = bid * 128;
    int l15  = lane & 15;
    int g4   = lane >> 4;

    f32x4 acc0[8], acc1[8];
    #pragma unroll
    for (int f = 0; f < 8; f++) {
        acc0[f] = (f32x4){0.f, 0.f, 0.f, 0.f};
        acc1[f] = (f32x4){0.f, 0.f, 0.f, 0.f};
    }

    int nstep = K >> 6;
    for (int st = 0; st < nstep; st++) {
        int kk  = st << 6;
        int seg = kk >> 7, kl = kk & 127;
        const ushort* Ap = (seg == 0) ? A0 : ((seg == 1) ? A1 : A2);

        // stage A: 1024 chunks of 16B in [ks][rb][lane] order.
        #pragma unroll
        for (int p = 0; p < 4; p++) {
            int q  = p*256 + t;
            int ks = q >> 9, rb = (q >> 6) & 7, l = q & 63;
            int row = row0 + rb*16 + (l & 15);
            row = (row < N) ? row : (N - 1);
            int k = kl + ks*32 + (l >> 4)*8;
            int qbase = p*256 + w*64;
            GLD_LDS16(Ap + (size_t)row*DIM + k, As + qbase*8);
        }
        // stage B: linear copy of 16 KB from packed Bt.
        #pragma unroll
        for (int p = 0; p < 4; p++) {
            int q = p*256 + t;
            int qbase = p*256 + w*64;
            GLD_LDS16(Bt + ((size_t)st*8192 + (size_t)q*8), Bs + qbase*8);
        }
        __syncthreads();

        #pragma unroll
        for (int ks = 0; ks < 2; ks++) {
            short8 a0 = *(const short8*)(&As[((ks*8 + w*2 + 0)*64 + lane)*8]);
            short8 a1 = *(const short8*)(&As[((ks*8 + w*2 + 1)*64 + lane)*8]);
            #pragma unroll
            for (int f = 0; f < 8; f++) {
                short8 bv = *(const short8*)(&Bs[((ks*8 + f)*64 + lane)*8]);
                acc0[f] = __builtin_amdgcn_mfma_f32_16x16x32_bf16(a0, bv, acc0[f], 0, 0, 0);
                acc1[f] = __builtin_amdgcn_mfma_f32_16x16x32_bf16(a1, bv, acc1[f], 0, 0, 0);
            }
        }
        __syncthreads();
    }

    // epilogue: bias + LN + ReLU + bf16 store.
    float bv[8], gv[8], bbv[8];
    #pragma unroll
    for (int f = 0; f < 8; f++) {
        bv[f]  = bias[f*16 + l15];
        gv[f]  = lng [f*16 + l15];
        bbv[f] = lnbb[f*16 + l15];
    }
    #pragma unroll
    for (int r2 = 0; r2 < 2; r2++) {
        #pragma unroll
        for (int i = 0; i < 4; i++) {
            int grow = row0 + w*32 + r2*16 + g4*4 + i;
            float vv[8];
            float s = 0.f, sq = 0.f;
            #pragma unroll
            for (int f = 0; f < 8; f++) {
                float av = r2 ? acc1[f][i] : acc0[f][i];
                vv[f] = av + bv[f];
                s  += vv[f];
                sq += vv[f] * vv[f];
            }
            s += __shfl_xor(s, 1);  sq += __shfl_xor(sq, 1);
            s += __shfl_xor(s, 2);  sq += __shfl_xor(sq, 2);
            s += __shfl_xor(s, 4);  sq += __shfl_xor(sq, 4);
            s += __shfl_xor(s, 8);  sq += __shfl_xor(sq, 8);
            float m   = s * (1.f/128.f);
            float var = sq * (1.f/128.f) - m*m;
            float rr  = rsqrtf(var + 1e-5f);
            if (grow < N) {
                #pragma unroll
                for (int f = 0; f < 8; f++) {
                    float y = (vv[f] - m) * rr * gv[f] + bbv[f];
                    y = fmaxf(y, 0.f);
                    out[(size_t)grow*DIM + f*16 + l15] = f2b(y);
                }
            }
        }
    }
}

// ---------------------------------------------------------------------------
// Head: out[N][16] = xp(bf16)[N][128] @ Wh[128][16] + bh.  16 rows/block.
__global__ __launch_bounds__(256) void head_kernel(
    const ushort* __restrict__ xp, const float* __restrict__ Wh,
    const float* __restrict__ bh, float* __restrict__ out)
{
    __shared__ float Xs[16*128];
    __shared__ float Ws[128*16];
    int t = threadIdx.x;
    int row0 = blockIdx.x * 16;
    for (int i = t; i < 2048; i += 256) Ws[i] = Wh[i];
    {
        int r = t >> 4, k8 = (t & 15) * 8;
        int gr = row0 + r;
        if (gr < NPAPER) {
            uint4 v = *(const uint4*)(xp + (size_t)gr*DIM + k8);
            const ushort* pv = (const ushort*)&v;
            #pragma unroll
            for (int i = 0; i < 8; i++) Xs[r*128 + k8 + i] = b2f(pv[i]);
        } else {
            #pragma unroll
            for (int i = 0; i < 8; i++) Xs[r*128 + k8 + i] = 0.f;
        }
    }
    __syncthreads();
    int r = t >> 4, c = t & 15;
    float acc = bh[c];
    #pragma unroll 16
    for (int k = 0; k < 128; k++) acc += Xs[r*128 + k] * Ws[k*16 + c];
    int gr = row0 + r;
    if (gr < NPAPER) out[(size_t)gr*NCLS + c] = acc;
}

// ---------------------------------------------------------------------------
extern "C" void kernel_launch(void* const* d_in, const int* in_sizes, int n_in,
                              void* d_out, int out_size, void* d_ws, size_t ws_size,
                              hipStream_t stream)
{
    const float* x_paper  = (const float*)d_in[0];
    const float* x_author = (const float*)d_in[1];
    const int*   ei_cites = (const int*)d_in[2];
    const int*   ei_writes= (const int*)d_in[3];
    const int*   ei_rev   = (const int*)d_in[4];
    const float* Wl       = (const float*)d_in[5];
    const float* Wr       = (const float*)d_in[6];
    const float* bl       = (const float*)d_in[7];
    const float* linp     = (const float*)d_in[8];
    const float* lina     = (const float*)d_in[9];
    const float* ln_s     = (const float*)d_in[10];
    const float* ln_b     = (const float*)d_in[11];
    const float* Wh       = (const float*)d_in[12];
    const float* bh       = (const float*)d_in[13];
    float* out = (float*)d_out;

    float* ws = (float*)d_ws;
    size_t off = 0;
    float* Bp     = ws + off; off += 2*384*128;
    float* Ba     = ws + off; off += 2*256*128;
    float* biasp  = ws + off; off += 2*128;
    float* biasa  = ws + off; off += 2*128;
    float* biasp2 = ws + off; off += 2*128;
    float* biasa2 = ws + off; off += 2*128;

    ushort* uws = (ushort*)(ws + off);
    size_t uoff = 0;
    ushort* xpb0 = uws + uoff; uoff += (size_t)NPAPER * DIM;
    ushort* xab0 = uws + uoff; uoff += (size_t)NAUTH  * DIM;
    ushort* xpb1 = uws + uoff; uoff += (size_t)NPAPER * DIM;
    ushort* xab1 = uws + uoff; uoff += (size_t)NAUTH  * DIM;
    ushort* aggC = uws + uoff; uoff += (size_t)NPAPER * DIM;
    ushort* aggW = uws + uoff; uoff += (size_t)NPAPER * DIM;
    ushort* aggR = uws + uoff; uoff += (size_t)NAUTH  * DIM;
    ushort* Btp  = uws + uoff; uoff += 2*49152;
    ushort* Bta  = uws + uoff; uoff += 2*32768;
    if (uoff & 1) uoff++;

    int* iws = (int*)(uws + uoff);
    size_t ioff = 0;
    int* rowAll = iws + ioff; ioff += NTOT + 1;
    int* cursor = iws + ioff; ioff += NTOT;
    int* deg    = iws + ioff; ioff += NTOT;
    int* colAll = iws + ioff; ioff += 3*NEDGE;
    int* bsum   = iws + ioff; ioff += 256;

    // ---- weight prep ----
    prep_weights<<<(2*384*128 + 2*256*128 + 512 + 255)/256, 256, 0, stream>>>(
        Wl, Wr, bl, Bp, Ba, biasp, biasa);
    build_bt<<<(2*128*384 + 2*128*256 + 255)/256, 256, 0, stream>>>(
        Bp, Ba, linp, lina, Btp, Bta);
    fold_bias<<<2, 256, 0, stream>>>(biasp, biasa, linp, lina, biasp2, biasa2);

    // ---- input conversion to bf16 (single launch) ----
    to_bf16_all<<<((NPAPER + NAUTH)*DIM/4 + 255)/256, 256, 0, stream>>>(
        x_paper, x_author, xpb0, xab0);

    // ---- consolidated CSR build ----
    hipMemsetAsync(deg, 0, (size_t)NTOT * 4, stream);
    deg_count3<<<(3*NEDGE + 255)/256, 256, 0, stream>>>(ei_cites, ei_writes, ei_rev, deg);
    {
        int nb = (NTOT + 1023) / 1024;   // 245 <= 256
        scan_pass1<<<nb, 256, 0, stream>>>(deg, NTOT, rowAll, bsum);
        scan_pass2<<<1, 256, 0, stream>>>(bsum, nb);
        scan_pass3<<<(NTOT + 256)/256 + 1, 256, 0, stream>>>(rowAll, NTOT, bsum, cursor);
    }
    csr_fill3<<<(3*NEDGE + 255)/256, 256, 0, stream>>>(ei_cites, ei_writes, ei_rev,
                                                       cursor, colAll);

    const int PBLK = (NPAPER + 127) / 128;
    const int ABLK = (NAUTH  + 127) / 128;

    // ---- 2 layers, ping-pong activations ----
    for (int l = 0; l < 2; l++) {
        const ushort* inp  = l ? xpb1 : xpb0;
        const ushort* ina  = l ? xab1 : xab0;
        ushort*       outp = l ? xpb0 : xpb1;
        ushort*       outa = l ? xab0 : xab1;

        gather3<<<NTOT*16/256, 256, 0, stream>>>(
            inp, ina, rowAll, colAll, aggC, aggW, aggR);

        gemm_ln2<<<PBLK + ABLK, 256, 0, stream>>>(
            aggC, aggW, aggR, inp, ina,
            Btp + (size_t)l*49152, Bta + (size_t)l*32768,
            biasp2 + l*128, biasa2 + l*128,
            ln_s + (size_t)l*256, ln_b + (size_t)l*256,
            outp, outa, PBLK);
    }

    // l=1 paper output landed in xpb0
    head_kernel<<<(NPAPER + 15)/16, 256, 0, stream>>>(xpb0, Wh, bh, out);
}

// Round 8
// 344.507 us; speedup vs baseline: 1.8419x; 1.2881x over previous
//
#include <hip/hip_runtime.h>
#include <math.h>

#define NPAPER 100000
#define NAUTH  50000
#define DIM    128
#define NEDGE  500000
#define NCLS   16
#define NTOT   (2*NPAPER + NAUTH)   // concatenated CSR node space (C | W | R)
#define NB     245                  // buckets of 1024 nodes over NTOT
#define CHUNK_A 11776               // edges per bucketize block
#define NBLK_A  128                 // ceil(3*NEDGE / CHUNK_A)

typedef unsigned int   uint;
typedef unsigned short ushort;
typedef unsigned char  uchar;
using short8 = __attribute__((ext_vector_type(8))) short;
using f32x4  = __attribute__((ext_vector_type(4))) float;

__device__ __forceinline__ float b2f(uint u) {
    return __uint_as_float(u << 16);
}
__device__ __forceinline__ ushort f2b(float f) {   // round-to-nearest-even
    uint x = __float_as_uint(f);
    return (ushort)((x + 0x7fffu + ((x >> 16) & 1u)) >> 16);
}

// global_load_lds: linear LDS dest (wave base + lane*16), per-lane global src.
#define GLD_LDS16(srcp, ldsp) \
    __builtin_amdgcn_global_load_lds( \
        (const __attribute__((address_space(1))) void*)(srcp), \
        (__attribute__((address_space(3))) void*)(ldsp), 16, 0, 0)

// ---------------------------------------------------------------------------
// prep 1: Bp[l]: [384][128] k-major f32 = [Wl0^T; Wl1^T; (Wr0+Wr1)^T]
//         Ba[l]: [256][128] = [Wl2^T; Wr2^T];  biasp/biasa
__global__ __launch_bounds__(256) void prep_weights(
    const float* __restrict__ Wl, const float* __restrict__ Wr,
    const float* __restrict__ bl,
    float* __restrict__ Bp, float* __restrict__ Ba,
    float* __restrict__ biasp, float* __restrict__ biasa)
{
    int t = blockIdx.x * 256 + threadIdx.x;
    if (t < 2*384*128) {
        int l = t / (384*128); int rem = t - l*(384*128);
        int k = rem >> 7, j = rem & 127;
        float v;
        if (k < 128)      v = Wl[((l*3+0)*128 + j)*128 + k];
        else if (k < 256) v = Wl[((l*3+1)*128 + j)*128 + (k-128)];
        else              v = Wr[((l*3+0)*128 + j)*128 + (k-256)]
                            + Wr[((l*3+1)*128 + j)*128 + (k-256)];
        Bp[t] = v;
        return;
    }
    t -= 2*384*128;
    if (t < 2*256*128) {
        int l = t / (256*128); int rem = t - l*(256*128);
        int k = rem >> 7, j = rem & 127;
        Ba[t] = (k < 128) ? Wl[((l*3+2)*128 + j)*128 + k]
                          : Wr[((l*3+2)*128 + j)*128 + (k-128)];
        return;
    }
    t -= 2*256*128;
    if (t < 256) { int l=t>>7, j=t&127; biasp[t] = bl[(l*3+0)*128+j] + bl[(l*3+1)*128+j]; return; }
    t -= 256;
    if (t < 256) { int l=t>>7, j=t&127; biasa[t] = bl[(l*3+2)*128+j]; return; }
}

// prep 2: residual fold + bf16 + PACK into MFMA-fragment order.
// Per 64-k step: [ks(2)][f(8)][lane(64)][8 elems]; staging = pure linear copy.
__device__ __forceinline__ size_t pack_off(int j, int k) {
    int kstep = k >> 6, ks = (k >> 5) & 1, g4 = (k >> 3) & 3, jj = k & 7;
    int f = j >> 4, l15 = j & 15;
    return (size_t)kstep*8192 + (size_t)(ks*512 + f*64 + g4*16 + l15)*8 + jj;
}

__global__ __launch_bounds__(256) void build_bt(
    const float* __restrict__ Bp, const float* __restrict__ Ba,
    const float* __restrict__ linp, const float* __restrict__ lina,
    ushort* __restrict__ Btp, ushort* __restrict__ Bta)
{
    int t = blockIdx.x * 256 + threadIdx.x;
    if (t < 2*128*384) {
        int l = t / (128*384); int rem = t - l*(128*384);
        int j = rem / 384, k = rem - j*384;
        const float* brow = Bp + (size_t)l*384*128 + (size_t)k*128;
        float v = brow[j];
        if (l == 0) {
            const float* lrow = linp + (size_t)j*128;
            float s = 0.f;
            #pragma unroll 8
            for (int m = 0; m < 128; m++) s += brow[m] * lrow[m];
            v += s;
        }
        Btp[(size_t)l*49152 + pack_off(j, k)] = f2b(v);
        return;
    }
    t -= 2*128*384;
    if (t < 2*128*256) {
        int l = t / (128*256); int rem = t - l*(128*256);
        int j = rem / 256, k = rem - j*256;
        const float* brow = Ba + (size_t)l*256*128 + (size_t)k*128;
        float v = brow[j];
        if (l == 0) {
            const float* lrow = lina + (size_t)j*128;
            float s = 0.f;
            #pragma unroll 8
            for (int m = 0; m < 128; m++) s += brow[m] * lrow[m];
            v += s;
        }
        Bta[(size_t)l*32768 + pack_off(j, k)] = f2b(v);
    }
}

// prep 3: bias' = bias @ (I + lin^T) for l=0 (pass-through l=1)
__global__ __launch_bounds__(256) void fold_bias(
    const float* __restrict__ biasp, const float* __restrict__ biasa,
    const float* __restrict__ linp, const float* __restrict__ lina,
    float* __restrict__ biasp2, float* __restrict__ biasa2)
{
    int t = blockIdx.x * 256 + threadIdx.x;   // 512 total
    if (t < 512) {
        int isa = t >> 8; int r = t & 255;
        int l = r >> 7, j = r & 127;
        const float* bsrc = isa ? biasa : biasp;
        const float* lin  = isa ? lina  : linp;
        float v = bsrc[r];
        if (l == 0) {
            float s = 0.f;
            for (int k = 0; k < 128; k++) s += bsrc[k] * lin[j*128 + k];
            v += s;
        }
        (isa ? biasa2 : biasp2)[r] = v;
    }
}

// ---------------------------------------------------------------------------
// fp32 -> bf16 conversion for BOTH inputs in one launch; 4 elems/thread.
__global__ __launch_bounds__(256) void to_bf16_all(
    const float* __restrict__ xp, const float* __restrict__ xa,
    ushort* __restrict__ yp, ushort* __restrict__ ya)
{
    int i = blockIdx.x * 256 + threadIdx.x;
    const int n4p = NPAPER * DIM / 4;
    const int n4a = NAUTH  * DIM / 4;
    const float* x; ushort* y;
    if (i < n4p) { x = xp; y = yp; }
    else if (i < n4p + n4a) { x = xa; y = ya; i -= n4p; }
    else return;
    float4 v = ((const float4*)x)[i];
    uint2 o;
    o.x = (uint)f2b(v.x) | ((uint)f2b(v.y) << 16);
    o.y = (uint)f2b(v.z) | ((uint)f2b(v.w) << 16);
    ((uint2*)y)[i] = o;
}

// ---------------------------------------------------------------------------
// Bucketed CSR build.  Node space g in [0, NTOT) = [papers(C)|papers(W)|authors(R)],
// bucket = g >> 10 (1024 nodes/bucket, NB=245).
// Concatenated edge index i in [0, 3E): tpe = i/NEDGE.
__device__ __forceinline__ int edge_g(const int* __restrict__ eiC,
                                      const int* __restrict__ eiW,
                                      const int* __restrict__ eiR, int i)
{
    int tpe = (i >= 2*NEDGE) ? 2 : ((i >= NEDGE) ? 1 : 0);
    int e = i - tpe*NEDGE;
    const int* ei = (tpe == 0) ? eiC : ((tpe == 1) ? eiW : eiR);
    int base = (tpe == 0) ? 0 : ((tpe == 1) ? NPAPER : 2*NPAPER);
    return base + ei[NEDGE + e];
}

// Phase 1: per-bucket edge counts.
__global__ __launch_bounds__(256) void bucket_count(
    const int* __restrict__ eiC, const int* __restrict__ eiW,
    const int* __restrict__ eiR, int* __restrict__ bucketCount)
{
    __shared__ int h[256];
    int t = threadIdx.x;
    h[t] = 0;
    __syncthreads();
    int start = blockIdx.x * CHUNK_A;
    int n = 3*NEDGE - start; if (n > CHUNK_A) n = CHUNK_A;
    for (int i = t; i < n; i += 256)
        atomicAdd(&h[edge_g(eiC, eiW, eiR, start + i) >> 10], 1);
    __syncthreads();
    if (h[t]) atomicAdd(&bucketCount[t], h[t]);
}

// Phase 2: exclusive scan over buckets (single block).
__global__ __launch_bounds__(256) void bucket_scan(
    const int* __restrict__ bucketCount, int* __restrict__ bucketBase,
    int* __restrict__ stageCursor)
{
    __shared__ int lds[256];
    int t = threadIdx.x;
    int v = (t < NB) ? bucketCount[t] : 0;
    lds[t] = v;
    __syncthreads();
    for (int o = 1; o < 256; o <<= 1) {
        int x = (t >= o) ? lds[t - o] : 0;
        __syncthreads();
        lds[t] += x;
        __syncthreads();
    }
    int ex = lds[t] - v;
    if (t < NB) { bucketBase[t] = ex; stageCursor[t] = ex; }
    if (t == 0) bucketBase[NB] = 3*NEDGE;
}

// Phase 3: emit edges bucket-clustered into stage[] as (g, src), with
// position-sorted writes (bursty, ~46 consecutive edges per bucket per block).
__global__ __launch_bounds__(256) void bucket_emit(
    const int* __restrict__ eiC, const int* __restrict__ eiW,
    const int* __restrict__ eiR,
    int* __restrict__ stageCursor, uint2* __restrict__ stage)
{
    __shared__ uchar  bId [CHUNK_A];
    __shared__ ushort rnk [CHUNK_A];
    __shared__ ushort perm[CHUNK_A];
    __shared__ uchar  posB[CHUNK_A];
    __shared__ int lcnt[256];
    __shared__ int lpre[256];
    __shared__ int bbase[256];
    int t = threadIdx.x;
    int start = blockIdx.x * CHUNK_A;
    int n = 3*NEDGE - start; if (n > CHUNK_A) n = CHUNK_A;
    lcnt[t] = 0;
    __syncthreads();
    // pass 1: bucket + rank per edge
    for (int i = t; i < n; i += 256) {
        int b = edge_g(eiC, eiW, eiR, start + i) >> 10;
        bId[i] = (uchar)b;
        rnk[i] = (ushort)atomicAdd(&lcnt[b], 1);
    }
    __syncthreads();
    // local inclusive scan of lcnt
    lpre[t] = lcnt[t];
    __syncthreads();
    for (int o = 1; o < 256; o <<= 1) {
        int x = (t >= o) ? lpre[t - o] : 0;
        __syncthreads();
        lpre[t] += x;
        __syncthreads();
    }
    // reserve global range per (block, bucket)
    if (lcnt[t] > 0) bbase[t] = atomicAdd(&stageCursor[t], lcnt[t]);
    __syncthreads();
    // pass 2: build position-sorted permutation
    for (int i = t; i < n; i += 256) {
        int b = bId[i];
        int p = (lpre[b] - lcnt[b]) + rnk[i];
        perm[p] = (ushort)i;
        posB[p] = (uchar)b;
    }
    __syncthreads();
    // pass 3: emit in position order -> coalesced bursty writes
    for (int p = t; p < n; p += 256) {
        int b = posB[p];
        int i = start + perm[p];
        int tpe = (i >= 2*NEDGE) ? 2 : ((i >= NEDGE) ? 1 : 0);
        int e = i - tpe*NEDGE;
        const int* ei = (tpe == 0) ? eiC : ((tpe == 1) ? eiW : eiR);
        int base = (tpe == 0) ? 0 : ((tpe == 1) ? NPAPER : 2*NPAPER);
        uint2 o2;
        o2.x = (uint)(base + ei[NEDGE + e]);
        o2.y = (uint)ei[e];
        stage[bbase[b] + (p - (lpre[b] - lcnt[b]))] = o2;
    }
}

// Phase 4: per-bucket CSR finalize: rowptr (coalesced) + col fill within a
// ~24 KB bucket-local window (page/L2-local writes).
__global__ __launch_bounds__(256) void csr_fillB(
    const uint2* __restrict__ stage, const int* __restrict__ bucketBase,
    int* __restrict__ rowAll, int* __restrict__ colAll)
{
    __shared__ int cnt[1024];
    __shared__ int part[256];
    int b = blockIdx.x;
    int t = threadIdx.x;
    int g0 = b << 10;
    int nn = NTOT - g0; if (nn > 1024) nn = 1024;
    int s = bucketBase[b], e = bucketBase[b+1];
    #pragma unroll
    for (int i = t; i < 1024; i += 256) cnt[i] = 0;
    __syncthreads();
    for (int i = s + t; i < e; i += 256) atomicAdd(&cnt[(int)stage[i].x - g0], 1);
    __syncthreads();
    int loc[4]; int ss = 0;
    #pragma unroll
    for (int j = 0; j < 4; j++) { loc[j] = cnt[t*4 + j]; ss += loc[j]; }
    part[t] = ss;
    __syncthreads();
    for (int o = 1; o < 256; o <<= 1) {
        int x = (t >= o) ? part[t - o] : 0;
        __syncthreads();
        part[t] += x;
        __syncthreads();
    }
    int run = (t > 0) ? part[t-1] : 0;
    #pragma unroll
    for (int j = 0; j < 4; j++) { int c = loc[j]; cnt[t*4 + j] = run; run += c; }
    __syncthreads();
    for (int i = t; i < nn; i += 256) rowAll[g0 + i] = s + cnt[i];
    if (b == NB-1 && t == 0) rowAll[NTOT] = 3*NEDGE;
    __syncthreads();
    for (int i = s + t; i < e; i += 256) {
        uint2 ed = stage[i];
        int slot = atomicAdd(&cnt[(int)ed.x - g0], 1);
        colAll[s + slot] = (int)ed.y;
    }
}

// ---------------------------------------------------------------------------
// Gather-mean over the consolidated CSR, all 3 edge types in one launch.
// 16 lanes per node (16B/lane row chunks), 4-deep load pipeline with dual
// accumulators for latency hiding.
__device__ __forceinline__ void acc8(float* a, uint4 v) {
    a[0] += b2f(v.x & 0xffffu); a[1] += b2f(v.x >> 16);
    a[2] += b2f(v.y & 0xffffu); a[3] += b2f(v.y >> 16);
    a[4] += b2f(v.z & 0xffffu); a[5] += b2f(v.z >> 16);
    a[6] += b2f(v.w & 0xffffu); a[7] += b2f(v.w >> 16);
}

__global__ __launch_bounds__(256) void gather3(
    const ushort* __restrict__ xp, const ushort* __restrict__ xa,
    const int* __restrict__ rowAll, const int* __restrict__ colAll,
    ushort* __restrict__ aggC, ushort* __restrict__ aggW,
    ushort* __restrict__ aggR)
{
    int g    = (blockIdx.x * 256 + threadIdx.x) >> 4;
    int lane = threadIdx.x & 15;
    if (g >= NTOT) return;
    const ushort* xs; ushort* out; int node;
    if (g < NPAPER)        { node = g;            xs = xp; out = aggC; }
    else if (g < 2*NPAPER) { node = g - NPAPER;   xs = xa; out = aggW; }
    else                   { node = g - 2*NPAPER; xs = xp; out = aggR; }

    int s = rowAll[g], e = rowAll[g + 1];
    float a[8] = {0,0,0,0,0,0,0,0};
    float b[8] = {0,0,0,0,0,0,0,0};
    int j = s;
    #pragma unroll 1
    for (; j + 4 <= e; j += 4) {
        int s0 = colAll[j], s1 = colAll[j+1], s2 = colAll[j+2], s3 = colAll[j+3];
        uint4 v0 = *(const uint4*)(xs + (size_t)s0 * DIM + lane * 8);
        uint4 v1 = *(const uint4*)(xs + (size_t)s1 * DIM + lane * 8);
        uint4 v2 = *(const uint4*)(xs + (size_t)s2 * DIM + lane * 8);
        uint4 v3 = *(const uint4*)(xs + (size_t)s3 * DIM + lane * 8);
        acc8(a, v0);
        acc8(b, v1);
        acc8(a, v2);
        acc8(b, v3);
    }
    #pragma unroll 1
    for (; j < e; j++) {
        uint4 v0 = *(const uint4*)(xs + (size_t)colAll[j] * DIM + lane * 8);
        acc8(a, v0);
    }
    float inv = (e > s) ? 1.f / (float)(e - s) : 0.f;
    #pragma unroll
    for (int i = 0; i < 8; i++) a[i] = (a[i] + b[i]) * inv;
    uint4 o;
    o.x = (uint)f2b(a[0]) | ((uint)f2b(a[1]) << 16);
    o.y = (uint)f2b(a[2]) | ((uint)f2b(a[3]) << 16);
    o.z = (uint)f2b(a[4]) | ((uint)f2b(a[5]) << 16);
    o.w = (uint)f2b(a[6]) | ((uint)f2b(a[7]) << 16);
    *(uint4*)(out + (size_t)node * DIM + lane * 8) = o;
}

// ---------------------------------------------------------------------------
// Merged MFMA GEMM + bias + LayerNorm + ReLU for BOTH node types, one launch.
// Blocks [0, pblk): paper rows (K=384, segs aggC|aggW|self-p).
// Blocks [pblk, ..): author rows (K=256, segs aggR|self-a).
// Block: 256 thr (4 waves), 128 rows (wave owns 32), full N=128, K-step 64.
// LDS fragment-contiguous; A via global_load_lds w/ swizzled global source,
// B staged linearly from pre-packed Bt.  All frag reads conflict-free.
__global__ __launch_bounds__(256) void gemm_ln2(
    const ushort* __restrict__ aggC, const ushort* __restrict__ aggW,
    const ushort* __restrict__ aggR,
    const ushort* __restrict__ xp, const ushort* __restrict__ xa,
    const ushort* __restrict__ Btp, const ushort* __restrict__ Bta,
    const float* __restrict__ biasp, const float* __restrict__ biasa,
    const float* __restrict__ lns, const float* __restrict__ lnb,  // [paper|author] 2*128
    ushort* __restrict__ outp, ushort* __restrict__ outa, int pblk)
{
    __shared__ ushort As[8192];   // 16 KB, one K-step
    __shared__ ushort Bs[8192];   // 16 KB

    bool isp = (int)blockIdx.x < pblk;
    int  bid = isp ? blockIdx.x : (blockIdx.x - pblk);
    int  N   = isp ? NPAPER : NAUTH;
    int  K   = isp ? 384 : 256;
    const ushort* A0 = isp ? aggC : aggR;
    const ushort* A1 = isp ? aggW : xa;
    const ushort* A2 = isp ? xp   : xa;
    const ushort* Bt = isp ? Btp  : Bta;
    const float* bias = isp ? biasp : biasa;
    const float* lng  = lns + (isp ? 0 : 128);
    const float* lnbb = lnb + (isp ? 0 : 128);
    ushort* out = isp ? outp : outa;

    int t    = threadIdx.x;
    int w    = t >> 6;
    int lane = t & 63;
    int row0 = bid * 128;
    int l15  = lane & 15;
    int g4   = lane >> 4;

    f32x4 acc0[8], acc1[8];
    #pragma unroll
    for (int f = 0; f < 8; f++) {
        acc0[f] = (f32x4){0.f, 0.f, 0.f, 0.f};
        acc1[f] = (f32x4){0.f, 0.f, 0.f, 0.f};
    }

    int nstep = K >> 6;
    for (int st = 0; st < nstep; st++) {
        int kk  = st << 6;
        int seg = kk >> 7, kl = kk & 127;
        const ushort* Ap = (seg == 0) ? A0 : ((seg == 1) ? A1 : A2);

        // stage A: 1024 chunks of 16B in [ks][rb][lane] order.
        #pragma unroll
        for (int p = 0; p < 4; p++) {
            int q  = p*256 + t;
            int ks = q >> 9, rb = (q >> 6) & 7, l = q & 63;
            int row = row0 + rb*16 + (l & 15);
            row = (row < N) ? row : (N - 1);
            int k = kl + ks*32 + (l >> 4)*8;
            int qbase = p*256 + w*64;
            GLD_LDS16(Ap + (size_t)row*DIM + k, As + qbase*8);
        }
        // stage B: linear copy of 16 KB from packed Bt.
        #pragma unroll
        for (int p = 0; p < 4; p++) {
            int q = p*256 + t;
            int qbase = p*256 + w*64;
            GLD_LDS16(Bt + ((size_t)st*8192 + (size_t)q*8), Bs + qbase*8);
        }
        __syncthreads();

        #pragma unroll
        for (int ks = 0; ks < 2; ks++) {
            short8 a0 = *(const short8*)(&As[((ks*8 + w*2 + 0)*64 + lane)*8]);
            short8 a1 = *(const short8*)(&As[((ks*8 + w*2 + 1)*64 + lane)*8]);
            #pragma unroll
            for (int f = 0; f < 8; f++) {
                short8 bv = *(const short8*)(&Bs[((ks*8 + f)*64 + lane)*8]);
                acc0[f] = __builtin_amdgcn_mfma_f32_16x16x32_bf16(a0, bv, acc0[f], 0, 0, 0);
                acc1[f] = __builtin_amdgcn_mfma_f32_16x16x32_bf16(a1, bv, acc1[f], 0, 0, 0);
            }
        }
        __syncthreads();
    }

    // epilogue: bias + LN + ReLU + bf16 store.
    float bv[8], gv[8], bbv[8];
    #pragma unroll
    for (int f = 0; f < 8; f++) {
        bv[f]  = bias[f*16 + l15];
        gv[f]  = lng [f*16 + l15];
        bbv[f] = lnbb[f*16 + l15];
    }
    #pragma unroll
    for (int r2 = 0; r2 < 2; r2++) {
        #pragma unroll
        for (int i = 0; i < 4; i++) {
            int grow = row0 + w*32 + r2*16 + g4*4 + i;
            float vv[8];
            float s = 0.f, sq = 0.f;
            #pragma unroll
            for (int f = 0; f < 8; f++) {
                float av = r2 ? acc1[f][i] : acc0[f][i];
                vv[f] = av + bv[f];
                s  += vv[f];
                sq += vv[f] * vv[f];
            }
            s += __shfl_xor(s, 1);  sq += __shfl_xor(sq, 1);
            s += __shfl_xor(s, 2);  sq += __shfl_xor(sq, 2);
            s += __shfl_xor(s, 4);  sq += __shfl_xor(sq, 4);
            s += __shfl_xor(s, 8);  sq += __shfl_xor(sq, 8);
            float m   = s * (1.f/128.f);
            float var = sq * (1.f/128.f) - m*m;
            float rr  = rsqrtf(var + 1e-5f);
            if (grow < N) {
                #pragma unroll
                for (int f = 0; f < 8; f++) {
                    float y = (vv[f] - m) * rr * gv[f] + bbv[f];
                    y = fmaxf(y, 0.f);
                    out[(size_t)grow*DIM + f*16 + l15] = f2b(y);
                }
            }
        }
    }
}

// ---------------------------------------------------------------------------
// Head: out[N][16] = xp(bf16)[N][128] @ Wh[128][16] + bh.  16 rows/block.
__global__ __launch_bounds__(256) void head_kernel(
    const ushort* __restrict__ xp, const float* __restrict__ Wh,
    const float* __restrict__ bh, float* __restrict__ out)
{
    __shared__ float Xs[16*128];
    __shared__ float Ws[128*16];
    int t = threadIdx.x;
    int row0 = blockIdx.x * 16;
    for (int i = t; i < 2048; i += 256) Ws[i] = Wh[i];
    {
        int r = t >> 4, k8 = (t & 15) * 8;
        int gr = row0 + r;
        if (gr < NPAPER) {
            uint4 v = *(const uint4*)(xp + (size_t)gr*DIM + k8);
            const ushort* pv = (const ushort*)&v;
            #pragma unroll
            for (int i = 0; i < 8; i++) Xs[r*128 + k8 + i] = b2f(pv[i]);
        } else {
            #pragma unroll
            for (int i = 0; i < 8; i++) Xs[r*128 + k8 + i] = 0.f;
        }
    }
    __syncthreads();
    int r = t >> 4, c = t & 15;
    float acc = bh[c];
    #pragma unroll 16
    for (int k = 0; k < 128; k++) acc += Xs[r*128 + k] * Ws[k*16 + c];
    int gr = row0 + r;
    if (gr < NPAPER) out[(size_t)gr*NCLS + c] = acc;
}

// ---------------------------------------------------------------------------
extern "C" void kernel_launch(void* const* d_in, const int* in_sizes, int n_in,
                              void* d_out, int out_size, void* d_ws, size_t ws_size,
                              hipStream_t stream)
{
    const float* x_paper  = (const float*)d_in[0];
    const float* x_author = (const float*)d_in[1];
    const int*   ei_cites = (const int*)d_in[2];
    const int*   ei_writes= (const int*)d_in[3];
    const int*   ei_rev   = (const int*)d_in[4];
    const float* Wl       = (const float*)d_in[5];
    const float* Wr       = (const float*)d_in[6];
    const float* bl       = (const float*)d_in[7];
    const float* linp     = (const float*)d_in[8];
    const float* lina     = (const float*)d_in[9];
    const float* ln_s     = (const float*)d_in[10];
    const float* ln_b     = (const float*)d_in[11];
    const float* Wh       = (const float*)d_in[12];
    const float* bh       = (const float*)d_in[13];
    float* out = (float*)d_out;

    float* ws = (float*)d_ws;
    size_t off = 0;
    float* Bp     = ws + off; off += 2*384*128;
    float* Ba     = ws + off; off += 2*256*128;
    float* biasp  = ws + off; off += 2*128;
    float* biasa  = ws + off; off += 2*128;
    float* biasp2 = ws + off; off += 2*128;
    float* biasa2 = ws + off; off += 2*128;

    ushort* uws = (ushort*)(ws + off);
    size_t uoff = 0;
    ushort* xpb0 = uws + uoff; uoff += (size_t)NPAPER * DIM;
    ushort* xab0 = uws + uoff; uoff += (size_t)NAUTH  * DIM;
    ushort* xpb1 = uws + uoff; uoff += (size_t)NPAPER * DIM;
    ushort* xab1 = uws + uoff; uoff += (size_t)NAUTH  * DIM;
    ushort* aggC = uws + uoff; uoff += (size_t)NPAPER * DIM;
    ushort* aggW = uws + uoff; uoff += (size_t)NPAPER * DIM;
    ushort* aggR = uws + uoff; uoff += (size_t)NAUTH  * DIM;
    ushort* Btp  = uws + uoff; uoff += 2*49152;
    ushort* Bta  = uws + uoff; uoff += 2*32768;
    if (uoff & 3) uoff += 4 - (uoff & 3);   // 8B-align what follows

    uint2* stage = (uint2*)(uws + uoff);    // 3E uint2 = 12 MB
    int* iws = (int*)(stage + 3*NEDGE);
    size_t ioff = 0;
    int* rowAll      = iws + ioff; ioff += NTOT + 1;
    int* colAll      = iws + ioff; ioff += 3*NEDGE;
    int* bucketCount = iws + ioff; ioff += 256;
    int* bucketBase  = iws + ioff; ioff += 256 + 1;
    int* stageCursor = iws + ioff; ioff += 256;

    // ---- weight prep ----
    prep_weights<<<(2*384*128 + 2*256*128 + 512 + 255)/256, 256, 0, stream>>>(
        Wl, Wr, bl, Bp, Ba, biasp, biasa);
    build_bt<<<(2*128*384 + 2*128*256 + 255)/256, 256, 0, stream>>>(
        Bp, Ba, linp, lina, Btp, Bta);
    fold_bias<<<2, 256, 0, stream>>>(biasp, biasa, linp, lina, biasp2, biasa2);

    // ---- input conversion to bf16 (single launch) ----
    to_bf16_all<<<((NPAPER + NAUTH)*DIM/4 + 255)/256, 256, 0, stream>>>(
        x_paper, x_author, xpb0, xab0);

    // ---- bucketed CSR build ----
    hipMemsetAsync(bucketCount, 0, 256*4, stream);
    bucket_count<<<NBLK_A, 256, 0, stream>>>(ei_cites, ei_writes, ei_rev, bucketCount);
    bucket_scan<<<1, 256, 0, stream>>>(bucketCount, bucketBase, stageCursor);
    bucket_emit<<<NBLK_A, 256, 0, stream>>>(ei_cites, ei_writes, ei_rev,
                                            stageCursor, stage);
    csr_fillB<<<NB, 256, 0, stream>>>(stage, bucketBase, rowAll, colAll);

    const int PBLK = (NPAPER + 127) / 128;
    const int ABLK = (NAUTH  + 127) / 128;

    // ---- 2 layers, ping-pong activations ----
    for (int l = 0; l < 2; l++) {
        const ushort* inp  = l ? xpb1 : xpb0;
        const ushort* ina  = l ? xab1 : xab0;
        ushort*       outp = l ? xpb0 : xpb1;
        ushort*       outa = l ? xab0 : xab1;

        gather3<<<NTOT*16/256, 256, 0, stream>>>(
            inp, ina, rowAll, colAll, aggC, aggW, aggR);

        gemm_ln2<<<PBLK + ABLK, 256, 0, stream>>>(
            aggC, aggW, aggR, inp, ina,
            Btp + (size_t)l*49152, Bta + (size_t)l*32768,
            biasp2 + l*128, biasa2 + l*128,
            ln_s + (size_t)l*256, ln_b + (size_t)l*256,
            outp, outa, PBLK);
    }

    // l=1 paper output landed in xpb0
    head_kernel<<<(NPAPER + 15)/16, 256, 0, stream>>>(xpb0, Wh, bh, out);
}